// Round 6
// baseline (281.992 us; speedup 1.0000x reference)
//
#include <hip/hip_runtime.h>
#include <math.h>

// ---------------------------------------------------------------------------
// Round 15: R14 banked (slot-major LDS, conv_all 45.5us, clean traffic).
// Remaining ~172us is the 7-dispatch tail (each <45us, invisible in top-5).
// This round shrinks the tail:
//  (a) normdist_k = norm_k + dist_k + scale_k fused. 1024 blocks == 4/CU
//      co-resident (__launch_bounds__(256,4)); dist tile kept in registers;
//      device-atomic spin-gate replaces the scale_k dispatch; saves 2
//      dispatches + ~2.5MB round-trip traffic.
//  (b) fc_m converts f32 weights in-register (bit-identical f2bf) -> repack_k
//      drops the FC-cast pass (3072 -> 192 blocks).
// conv_all EXACTLY as R14. 6 dispatches total.
// ---------------------------------------------------------------------------

#define BN_EPS 1e-5f

typedef __attribute__((ext_vector_type(8))) short short8;   // 8 bf16 = 4 VGPR
typedef __attribute__((ext_vector_type(4))) float f32x4;

__device__ __forceinline__ unsigned short f2bf(float f) {
    unsigned u = __float_as_uint(f);
    u += 0x7fffu + ((u >> 16) & 1u);          // round-to-nearest-even
    return (unsigned short)(u >> 16);
}

__device__ __forceinline__ short8 f2bf8(float4 lo, float4 hi) {
    short8 r;
    r[0] = (short)f2bf(lo.x); r[1] = (short)f2bf(lo.y);
    r[2] = (short)f2bf(lo.z); r[3] = (short)f2bf(lo.w);
    r[4] = (short)f2bf(hi.x); r[5] = (short)f2bf(hi.y);
    r[6] = (short)f2bf(hi.z); r[7] = (short)f2bf(hi.w);
    return r;
}

// ---- conv weight repack + flag zeroing (FC weights now cast in fc_m) -------
__global__ __launch_bounds__(256) void repack_k(
    const float* __restrict__ w1, const float* __restrict__ w2,
    const float* __restrict__ w3,
    unsigned short* __restrict__ wT1b,
    unsigned short* __restrict__ wT2b, unsigned short* __restrict__ wT3b,
    unsigned* __restrict__ mxslot, unsigned* __restrict__ done)
{
    int t = blockIdx.x * 256 + threadIdx.x;
    if (t == 0) { *mxslot = 0u; *done = 0u; }
    if (t < 512) {
        int k = t & 31, oc = t >> 5;
        wT1b[t] = (k < 24) ? f2bf(w1[oc * 24 + k]) : (unsigned short)0;
    }
    if (t < 12288) {
        int k = t & 31, oc = (t >> 5) & 31, kk = t >> 10;
        int ky = kk >> 1, kxp = kk & 1;
        int hi = k >> 4, ic = k & 15;
        int kx = 2 * kxp + hi;
        wT2b[t] = f2bf(w2[((oc * 16 + ic) * 6 + ky) * 4 + kx]);
    }
    if (t < 49152) {
        int ic = t & 31, oc = (t >> 5) & 63, kk = t >> 11;
        int ky = kk >> 2, kx = kk & 3;
        wT3b[t] = f2bf(w3[((oc * 32 + ic) * 6 + ky) * 4 + kx]);
    }
}

// ---- conv_all: full conv stack, 1 block = 1 batch, 8 waves (R14, proven) ---
// s_out1 slot-major: plane p=ch>>3 in {0,1}; addr = p*11808 + cell*8 + (ch&7)
// s_un   slot-major: plane p=ch>>3 in {0..3}; addr = p*3840 + cell*8 + (ch&7)
// pa/pb row stride 70 ush; pb offset +4 ush (phase-A bank split).
__global__ __launch_bounds__(512) void conv_all(
    const float* __restrict__ x, const unsigned short* __restrict__ wT1,
    const unsigned short* __restrict__ wT2, const unsigned short* __restrict__ wT3,
    const float* __restrict__ c1b, const float* __restrict__ g1,
    const float* __restrict__ b1, const float* __restrict__ m1,
    const float* __restrict__ v1,
    const float* __restrict__ c2b, const float* __restrict__ g2,
    const float* __restrict__ b2, const float* __restrict__ m2,
    const float* __restrict__ v2,
    const float* __restrict__ c3b, const float* __restrict__ g3,
    const float* __restrict__ b3, const float* __restrict__ m3,
    const float* __restrict__ v3,
    unsigned short* __restrict__ out3)
{
    __shared__ __align__(16) unsigned short s_out1[2 * 1476 * 8];  // 47232 B
    __shared__ __align__(16) unsigned short s_un[4 * 480 * 8];     // 30720 B
    const int tid = threadIdx.x, nl = blockIdx.x;
    const int lane = tid & 63, wave = tid >> 6;
    const int n = lane & 15, q = lane >> 4;
    unsigned short* pa = s_un;           // [79][70]: pa[r][c] = img[r-2][c-1]
    unsigned short* pb = s_un + 5534;    // [79][70]: pb[r][c] = img[r-2][c-2]

    {
        unsigned* z32 = (unsigned*)s_un;
        for (int i = tid; i < 5532; i += 512) z32[i] = 0u;
        uint4 z4; z4.x = z4.y = z4.z = z4.w = 0u;
        for (int pc = tid; pc < 324; pc += 512) {
            int row, colc;
            if (pc < 180) { row = pc / 36; colc = pc % 36; if (row >= 2) row += 36; }
            else { int pz = pc - 180; row = 2 + (pz >> 2); colc = (pz & 3) ? 32 + (pz & 3) : 0; }
            int cc = row * 36 + colc;
            *(uint4*)(s_out1 + cc * 8) = z4;             // plane 0
            *(uint4*)(s_out1 + 11808 + cc * 8) = z4;     // plane 1
        }
    }
    __syncthreads();
    {
        const float4* src = (const float4*)(x + (size_t)nl * 4608);
        for (int i = tid; i < 1152; i += 512) {
            float4 val = src[i];
            int f = i * 4, row = (f >> 6) + 2, c = (f & 63) + 1;   // c odd
            unsigned short h0 = f2bf(val.x), h1 = f2bf(val.y);
            unsigned short h2 = f2bf(val.z), h3 = f2bf(val.w);
            unsigned short* ap = pa + row * 70 + c;
            ap[0] = h0; ap[1] = h1; ap[2] = h2; ap[3] = h3;
            unsigned* bp = (unsigned*)(pb + row * 70 + c + 1);     // even idx
            bp[0] = (unsigned)h0 | ((unsigned)h1 << 16);
            bp[1] = (unsigned)h2 | ((unsigned)h3 << 16);
        }
    }
    const float sc1 = g1[n] * rsqrtf(v1[n] + BN_EPS);
    const float bb1 = c1b[n];
    const float mm1 = b1[n] - m1[n] * sc1;
    const short8 bfr1 = *(const short8*)(wT1 + n * 32 + q * 8);
    __syncthreads();

    // phase A: conv1 (8 waves x 36 iters = 288 tiles)
    for (int i = 0; i < 36; ++i) {
        int t = wave * 36 + i;
        int pooled = 4 * t + (n >> 2);
        int ph = pooled >> 5, pw = pooled & 31;
        int py = (n >> 1) & 1, px = n & 1;
        int oh = 2 * ph + py, ow = 2 * pw + px;
        int r0 = (oh + 2 * q) * 70;
        const unsigned* base = px ? (const unsigned*)(pb + r0 + ow + 1)
                                  : (const unsigned*)(pa + r0 + ow);
        uint4 uu;
        uu.x = base[0];  uu.y = base[1];
        uu.z = base[35]; uu.w = base[36];
        short8 afr = *reinterpret_cast<short8*>(&uu);
        f32x4 acc = (f32x4){0.f, 0.f, 0.f, 0.f};
        acc = __builtin_amdgcn_mfma_f32_16x16x32_bf16(afr, bfr1, acc, 0, 0, 0);
        int po = 4 * t + q, oph = po >> 5, opw = po & 31;
        float mx = fmaxf(fmaxf(acc[0], acc[1]), fmaxf(acc[2], acc[3]));
        float val = fmaxf(mx + bb1, 0.f) * sc1 + mm1;
        int cc = (oph + 2) * 36 + (opw + 1);
        s_out1[(n >> 3) * 11808 + cc * 8 + (n & 7)] = f2bf(val);
    }
    __syncthreads();
    {
        uint4 z4; z4.x = z4.y = z4.z = z4.w = 0u;
        for (int pc = tid; pc < 192; pc += 512) {
            int row, colc;
            if (pc < 120) { row = pc / 20; colc = pc % 20; if (row >= 2) row += 18; }
            else { int pz = pc - 120; row = 2 + (pz >> 2); colc = (pz & 3) ? 16 + (pz & 3) : 0; }
            int cc = row * 20 + colc;
            *(uint4*)(s_un + cc * 8) = z4;
            *(uint4*)(s_un + 3840 + cc * 8) = z4;
            *(uint4*)(s_un + 7680 + cc * 8) = z4;
            *(uint4*)(s_un + 11520 + cc * 8) = z4;
        }
    }
    float bnb2[2], bns2[2], bnm2[2];
#pragma unroll
    for (int nt = 0; nt < 2; ++nt) {
        int oc = nt * 16 + n;
        float sc = g2[oc] * rsqrtf(v2[oc] + BN_EPS);
        bnb2[nt] = c2b[oc]; bns2[nt] = sc; bnm2[nt] = b2[oc] - m2[oc] * sc;
    }
    __syncthreads();

    // phase B: conv2 (36 tiles over 8 waves); reads base+immediate only
    for (int pp = wave; pp < 36; pp += 8) {
        int ph = pp >> 1, half = pp & 1;
        const unsigned short* bB = s_out1 + (q & 1) * 11808 + (q >> 1) * 8
                                   + (half * 16 + n) * 8 + (2 * ph) * 288;
        f32x4 acc[2][2];
#pragma unroll
        for (int ab = 0; ab < 2; ++ab)
#pragma unroll
            for (int nt = 0; nt < 2; ++nt) acc[ab][nt] = (f32x4){0.f, 0.f, 0.f, 0.f};
#pragma unroll
        for (int ky = 0; ky < 6; ++ky)
#pragma unroll
            for (int kxp = 0; kxp < 2; ++kxp) {
                int kk = ky * 2 + kxp;
                short8 w0 = *(const short8*)(wT2 + ((size_t)(kk * 32 + n) * 32) + q * 8);
                short8 w1 = *(const short8*)(wT2 + ((size_t)(kk * 32 + 16 + n) * 32) + q * 8);
#pragma unroll
                for (int ab = 0; ab < 2; ++ab) {
                    short8 afr = *(const short8*)(bB + ((ab + ky) * 288 + kxp * 16));
                    acc[ab][0] = __builtin_amdgcn_mfma_f32_16x16x32_bf16(afr, w0, acc[ab][0], 0, 0, 0);
                    acc[ab][1] = __builtin_amdgcn_mfma_f32_16x16x32_bf16(afr, w1, acc[ab][1], 0, 0, 0);
                }
            }
        int pw0 = half * 8 + q * 2;
#pragma unroll
        for (int nt = 0; nt < 2; ++nt) {
            int oc = nt * 16 + n;
            float p0 = fmaxf(fmaxf(acc[0][nt][0], acc[0][nt][1]),
                             fmaxf(acc[1][nt][0], acc[1][nt][1]));
            float p1 = fmaxf(fmaxf(acc[0][nt][2], acc[0][nt][3]),
                             fmaxf(acc[1][nt][2], acc[1][nt][3]));
            p0 = fmaxf(p0 + bnb2[nt], 0.f) * bns2[nt] + bnm2[nt];
            p1 = fmaxf(p1 + bnb2[nt], 0.f) * bns2[nt] + bnm2[nt];
            int cellA = (ph + 2) * 20 + pw0 + 1;
            int pl = (oc >> 3) * 3840, cl = oc & 7;
            s_un[pl + cellA * 8 + cl] = f2bf(p0);
            s_un[pl + (cellA + 1) * 8 + cl] = f2bf(p1);
        }
    }
    __syncthreads();

    // phase C: conv3 (12 tiles over 8 waves); reads base+immediate only
    for (int ch = wave; ch < 12; ch += 8) {
        int pr = ch >> 1, nth = ch & 1;
        const unsigned short* bC = s_un + q * 3840 + n * 8 + (3 * pr) * 160;
        f32x4 acc[3][2];
#pragma unroll
        for (int r = 0; r < 3; ++r)
#pragma unroll
            for (int t2 = 0; t2 < 2; ++t2) acc[r][t2] = (f32x4){0.f, 0.f, 0.f, 0.f};
#pragma unroll
        for (int ky = 0; ky < 6; ++ky)
#pragma unroll
            for (int kx = 0; kx < 4; ++kx) {
                int kk = ky * 4 + kx;
                short8 w0 = *(const short8*)(wT3 + ((size_t)(kk * 64 + nth * 32 + n) * 32) + q * 8);
                short8 w1 = *(const short8*)(wT3 + ((size_t)(kk * 64 + nth * 32 + 16 + n) * 32) + q * 8);
#pragma unroll
                for (int r = 0; r < 3; ++r) {
                    short8 afr = *(const short8*)(bC + ((r + ky) * 160 + kx * 8));
                    acc[r][0] = __builtin_amdgcn_mfma_f32_16x16x32_bf16(afr, w0, acc[r][0], 0, 0, 0);
                    acc[r][1] = __builtin_amdgcn_mfma_f32_16x16x32_bf16(afr, w1, acc[r][1], 0, 0, 0);
                }
            }
        size_t ob = (size_t)nl * 1536;
#pragma unroll
        for (int t2 = 0; t2 < 2; ++t2) {
            int oc = nth * 32 + t2 * 16 + n;
            float sc = g3[oc] * rsqrtf(v3[oc] + BN_EPS);
            float mx = -3.4e38f;
#pragma unroll
            for (int r = 0; r < 3; ++r)
#pragma unroll
                for (int e = 0; e < 4; ++e) mx = fmaxf(mx, acc[r][t2][e]);
            float val = fmaxf(mx + c3b[oc], 0.f) * sc + (b3[oc] - m3[oc] * sc);
            out3[ob + (size_t)oc * 24 + pr * 4 + q] = f2bf(val);
        }
    }
}

// ---- fc (MFMA, LDS-free, wide grid; prefetch + dual acc; f32 W in-reg cast)
__global__ __launch_bounds__(256) void fc_m(
    const unsigned short* __restrict__ A, const float* __restrict__ W,
    const float* __restrict__ bias, const float* __restrict__ g,
    const float* __restrict__ bt, const float* __restrict__ m,
    const float* __restrict__ v, unsigned short* __restrict__ out_b,
    float* __restrict__ out_f, int K, int N, int mode)   // mode 0=bf16, 1=f32
{
    const int tid = threadIdx.x;
    const int lane = tid & 63, wave = tid >> 6;
    const int n = lane & 15, q = lane >> 4;
    const int wr = wave >> 1, wc = wave & 1;
    const int r0 = blockIdx.y * 32 + wr * 16;
    const int c0 = blockIdx.x * 32 + wc * 16;
    const int col = c0 + n;

    float sc = g[col] * rsqrtf(v[col] + BN_EPS);
    float bb = bias[col];
    float mm = bt[col] - m[col] * sc;

    const unsigned short* Ap = A + (size_t)(r0 + n) * K + q * 8;
    const float* Bp = W + (size_t)col * K + q * 8;

    f32x4 acc0 = (f32x4){0.f, 0.f, 0.f, 0.f};
    f32x4 acc1 = (f32x4){0.f, 0.f, 0.f, 0.f};
    short8 a0 = *(const short8*)(Ap);
    short8 a1 = *(const short8*)(Ap + 32);
    short8 b0 = f2bf8(*(const float4*)(Bp), *(const float4*)(Bp + 4));
    short8 b1 = f2bf8(*(const float4*)(Bp + 32), *(const float4*)(Bp + 36));
#pragma unroll 2
    for (int kk = 64; kk < K; kk += 64) {
        short8 a0n = *(const short8*)(Ap + kk);
        short8 a1n = *(const short8*)(Ap + kk + 32);
        float4 c0a = *(const float4*)(Bp + kk);
        float4 c0b = *(const float4*)(Bp + kk + 4);
        float4 c1a = *(const float4*)(Bp + kk + 32);
        float4 c1b = *(const float4*)(Bp + kk + 36);
        acc0 = __builtin_amdgcn_mfma_f32_16x16x32_bf16(a0, b0, acc0, 0, 0, 0);
        acc1 = __builtin_amdgcn_mfma_f32_16x16x32_bf16(a1, b1, acc1, 0, 0, 0);
        a0 = a0n; a1 = a1n;
        b0 = f2bf8(c0a, c0b); b1 = f2bf8(c1a, c1b);
    }
    acc0 = __builtin_amdgcn_mfma_f32_16x16x32_bf16(a0, b0, acc0, 0, 0, 0);
    acc1 = __builtin_amdgcn_mfma_f32_16x16x32_bf16(a1, b1, acc1, 0, 0, 0);
#pragma unroll
    for (int e = 0; e < 4; ++e) {
        int row = r0 + q * 4 + e;
        float val = fmaxf(acc0[e] + acc1[e] + bb, 0.f) * sc + mm;
        if (mode == 0) out_b[(size_t)row * N + col] = f2bf(val);
        else           out_f[(size_t)row * N + col] = val;
    }
}

// ---- fused normalize + pairwise distance + global max + scale --------------
// grid 32x32 = 1024 blocks = exactly 4 blocks/CU; __launch_bounds__(256,4)
// guarantees co-residency -> device-atomic gate is deadlock-free.
__global__ __launch_bounds__(256, 4) void normdist_k(
    const float* __restrict__ f3, float* __restrict__ D,
    unsigned* __restrict__ mxslot, unsigned* __restrict__ done)
{
    __shared__ __align__(16) float Ei[16 * 132];
    __shared__ __align__(16) float Ej[16 * 132];
    __shared__ float sqi[16], sqj[16];
    __shared__ float red[256];
    const int tid = threadIdx.x;
    const int bi = blockIdx.y * 16, bj = blockIdx.x * 16;
    {
        int lr = tid >> 4, lc = (tid & 15) * 8;
        float4 a0 = *(const float4*)(f3 + (bi + lr) * 128 + lc);
        float4 a1 = *(const float4*)(f3 + (bi + lr) * 128 + lc + 4);
        float4 b0 = *(const float4*)(f3 + (bj + lr) * 128 + lc);
        float4 b1 = *(const float4*)(f3 + (bj + lr) * 128 + lc + 4);
        float sa = a0.x*a0.x + a0.y*a0.y + a0.z*a0.z + a0.w*a0.w
                 + a1.x*a1.x + a1.y*a1.y + a1.z*a1.z + a1.w*a1.w;
        float sb = b0.x*b0.x + b0.y*b0.y + b0.z*b0.z + b0.w*b0.w
                 + b1.x*b1.x + b1.y*b1.y + b1.z*b1.z + b1.w*b1.w;
#pragma unroll
        for (int mk = 1; mk <= 8; mk <<= 1) {
            sa += __shfl_xor(sa, mk, 64);
            sb += __shfl_xor(sb, mk, 64);
        }
        float nna = fmaxf(sqrtf(sa), 1e-12f);
        float nnb = fmaxf(sqrtf(sb), 1e-12f);
        a0.x /= nna; a0.y /= nna; a0.z /= nna; a0.w /= nna;
        a1.x /= nna; a1.y /= nna; a1.z /= nna; a1.w /= nna;
        b0.x /= nnb; b0.y /= nnb; b0.z /= nnb; b0.w /= nnb;
        b1.x /= nnb; b1.y /= nnb; b1.z /= nnb; b1.w /= nnb;
        *(float4*)(Ei + lr * 132 + lc) = a0;
        *(float4*)(Ei + lr * 132 + lc + 4) = a1;
        *(float4*)(Ej + lr * 132 + lc) = b0;
        *(float4*)(Ej + lr * 132 + lc + 4) = b1;
        if ((tid & 15) == 0) {
            sqi[lr] = sa / (nna * nna);
            sqj[lr] = sb / (nnb * nnb);
        }
    }
    __syncthreads();
    const int tx = tid & 15, ty = tid >> 4;
    float dot = 0.f;
#pragma unroll 4
    for (int k = 0; k < 128; k += 4) {
        float4 a = *(const float4*)(Ei + ty * 132 + k);
        float4 b = *(const float4*)(Ej + tx * 132 + k);
        dot = fmaf(a.x, b.x, dot); dot = fmaf(a.y, b.y, dot);
        dot = fmaf(a.z, b.z, dot); dot = fmaf(a.w, b.w, dot);
    }
    int i = bi + ty, j = bj + tx;
    float d2 = sqi[ty] + sqj[tx] - 2.f * dot;
    float dist = sqrtf(fmaxf(d2, 1e-12f));
    dist = (d2 > 0.f) ? dist : 0.f;
    if (i == j) dist = 0.f;
    red[tid] = dist;
    __syncthreads();
    for (int s2 = 128; s2 > 0; s2 >>= 1) {
        if (tid < s2) red[tid] = fmaxf(red[tid], red[tid + s2]);
        __syncthreads();
    }
    if (tid == 0) {
        atomicMax(mxslot, __float_as_uint(red[0]));
        __threadfence();
        atomicAdd(done, 1u);
        unsigned vv;
        do { __builtin_amdgcn_s_sleep(2); vv = atomicMax(done, 0u); }
        while (vv < 1024u);
        red[0] = __uint_as_float(atomicMax(mxslot, 0u));
    }
    __syncthreads();
    D[i * 512 + j] = dist / red[0];
}

// ---------------------------------------------------------------------------
extern "C" void kernel_launch(void* const* d_in, const int* in_sizes, int n_in,
                              void* d_out, int out_size, void* d_ws, size_t ws_size,
                              hipStream_t stream)
{
    (void)in_sizes; (void)n_in; (void)out_size; (void)ws_size;
    const float* x    = (const float*)d_in[0];
    const float* c1w  = (const float*)d_in[1];
    const float* c1b  = (const float*)d_in[2];
    const float* g1   = (const float*)d_in[3];
    const float* b1   = (const float*)d_in[4];
    const float* m1   = (const float*)d_in[5];
    const float* v1   = (const float*)d_in[6];
    const float* c2w  = (const float*)d_in[7];
    const float* c2b  = (const float*)d_in[8];
    const float* g2   = (const float*)d_in[9];
    const float* b2   = (const float*)d_in[10];
    const float* m2   = (const float*)d_in[11];
    const float* v2   = (const float*)d_in[12];
    const float* c3w  = (const float*)d_in[13];
    const float* c3b  = (const float*)d_in[14];
    const float* g3   = (const float*)d_in[15];
    const float* b3   = (const float*)d_in[16];
    const float* m3   = (const float*)d_in[17];
    const float* v3   = (const float*)d_in[18];
    const float* fw1  = (const float*)d_in[19];
    const float* fb1  = (const float*)d_in[20];
    const float* gf1  = (const float*)d_in[21];
    const float* bf1  = (const float*)d_in[22];
    const float* mf1  = (const float*)d_in[23];
    const float* vf1  = (const float*)d_in[24];
    const float* fw2  = (const float*)d_in[25];
    const float* fb2  = (const float*)d_in[26];
    const float* gf2  = (const float*)d_in[27];
    const float* bf2  = (const float*)d_in[28];
    const float* mf2  = (const float*)d_in[29];
    const float* vf2  = (const float*)d_in[30];
    const float* fw3  = (const float*)d_in[31];
    const float* fb3  = (const float*)d_in[32];
    const float* gf3  = (const float*)d_in[33];
    const float* bf3  = (const float*)d_in[34];
    const float* mf3  = (const float*)d_in[35];
    const float* vf3  = (const float*)d_in[36];

    float* ws = (float*)d_ws;
    // ---- ws layout (float offsets, 16B-aligned) ---------------------------
    float* f3v  = ws + 66048;                                // 65536
    unsigned* mx   = (unsigned*)(ws + 131584);
    unsigned* done = (unsigned*)(ws + 131585);
    unsigned short* wT1b = (unsigned short*)(ws + 131600);   // 512 ush
    unsigned short* wT2b = (unsigned short*)(ws + 131856);   // 12288 ush
    unsigned short* wT3b = (unsigned short*)(ws + 138000);   // 49152 ush
    unsigned short* out3b= (unsigned short*)(ws + 637712);   // 786432 ush
    unsigned short* a1b  = (unsigned short*)(ws + 1030928);  // 262144 ush
    unsigned short* a2b  = (unsigned short*)(ws + 1162000);  // 131072 ush

    float* out = (float*)d_out;

    repack_k<<<192, 256, 0, stream>>>(c1w, c2w, c3w, wT1b, wT2b, wT3b, mx, done);
    conv_all<<<512, 512, 0, stream>>>(x, wT1b, wT2b, wT3b,
                                      c1b, g1, b1, m1, v1,
                                      c2b, g2, b2, m2, v2,
                                      c3b, g3, b3, m3, v3, out3b);
    fc_m<<<dim3(16, 16), 256, 0, stream>>>(out3b, fw1, fb1, gf1, bf1, mf1, vf1,
                                           a1b, nullptr, 1536, 512, 0);
    fc_m<<<dim3(8, 16), 256, 0, stream>>>(a1b, fw2, fb2, gf2, bf2, mf2, vf2,
                                          a2b, nullptr, 512, 256, 0);
    fc_m<<<dim3(4, 16), 256, 0, stream>>>(a2b, fw3, fb3, gf3, bf3, mf3, vf3,
                                          nullptr, f3v, 256, 128, 1);
    normdist_k<<<dim3(32, 32), 256, 0, stream>>>(f3v, out, mx, done);
}

// Round 7
// 218.853 us; speedup vs baseline: 1.2885x; 1.2885x over previous
//
#include <hip/hip_runtime.h>
#include <math.h>

// ---------------------------------------------------------------------------
// Round 16: R15 post-mortem: normdist_k's grid-wide spin-gate cost ~65us
// (84us dispatch, 0% MFMA, 4% VALU — every block waits for the whole grid;
// 1024 spinners on one cacheline). Software grid barriers are ~30x more
// expensive than the 2 dispatches they save. REVERT to separate
// norm_k/dist_k/scale_k (R14-proven). KEEP slim repack (192 blocks) + fc_m
// in-register f32->bf16 weight cast (attributed this round vs R14).
// conv_all EXACTLY as R14 (45.5us, clean traffic). 8 dispatches.
// ---------------------------------------------------------------------------

#define BN_EPS 1e-5f

typedef __attribute__((ext_vector_type(8))) short short8;   // 8 bf16 = 4 VGPR
typedef __attribute__((ext_vector_type(4))) float f32x4;

__device__ __forceinline__ unsigned short f2bf(float f) {
    unsigned u = __float_as_uint(f);
    u += 0x7fffu + ((u >> 16) & 1u);          // round-to-nearest-even
    return (unsigned short)(u >> 16);
}

__device__ __forceinline__ short8 f2bf8(float4 lo, float4 hi) {
    short8 r;
    r[0] = (short)f2bf(lo.x); r[1] = (short)f2bf(lo.y);
    r[2] = (short)f2bf(lo.z); r[3] = (short)f2bf(lo.w);
    r[4] = (short)f2bf(hi.x); r[5] = (short)f2bf(hi.y);
    r[6] = (short)f2bf(hi.z); r[7] = (short)f2bf(hi.w);
    return r;
}

// ---- conv weight repack + mx zero (FC weights cast in fc_m) ----------------
__global__ __launch_bounds__(256) void repack_k(
    const float* __restrict__ w1, const float* __restrict__ w2,
    const float* __restrict__ w3,
    unsigned short* __restrict__ wT1b,
    unsigned short* __restrict__ wT2b, unsigned short* __restrict__ wT3b,
    unsigned* __restrict__ mxslot)
{
    int t = blockIdx.x * 256 + threadIdx.x;
    if (t == 0) *mxslot = 0u;
    if (t < 512) {
        int k = t & 31, oc = t >> 5;
        wT1b[t] = (k < 24) ? f2bf(w1[oc * 24 + k]) : (unsigned short)0;
    }
    if (t < 12288) {
        int k = t & 31, oc = (t >> 5) & 31, kk = t >> 10;
        int ky = kk >> 1, kxp = kk & 1;
        int hi = k >> 4, ic = k & 15;
        int kx = 2 * kxp + hi;
        wT2b[t] = f2bf(w2[((oc * 16 + ic) * 6 + ky) * 4 + kx]);
    }
    if (t < 49152) {
        int ic = t & 31, oc = (t >> 5) & 63, kk = t >> 11;
        int ky = kk >> 2, kx = kk & 3;
        wT3b[t] = f2bf(w3[((oc * 32 + ic) * 6 + ky) * 4 + kx]);
    }
}

// ---- conv_all: full conv stack, 1 block = 1 batch, 8 waves (R14, proven) ---
// s_out1 slot-major: plane p=ch>>3 in {0,1}; addr = p*11808 + cell*8 + (ch&7)
// s_un   slot-major: plane p=ch>>3 in {0..3}; addr = p*3840 + cell*8 + (ch&7)
// pa/pb row stride 70 ush; pb offset +4 ush (phase-A bank split).
__global__ __launch_bounds__(512) void conv_all(
    const float* __restrict__ x, const unsigned short* __restrict__ wT1,
    const unsigned short* __restrict__ wT2, const unsigned short* __restrict__ wT3,
    const float* __restrict__ c1b, const float* __restrict__ g1,
    const float* __restrict__ b1, const float* __restrict__ m1,
    const float* __restrict__ v1,
    const float* __restrict__ c2b, const float* __restrict__ g2,
    const float* __restrict__ b2, const float* __restrict__ m2,
    const float* __restrict__ v2,
    const float* __restrict__ c3b, const float* __restrict__ g3,
    const float* __restrict__ b3, const float* __restrict__ m3,
    const float* __restrict__ v3,
    unsigned short* __restrict__ out3)
{
    __shared__ __align__(16) unsigned short s_out1[2 * 1476 * 8];  // 47232 B
    __shared__ __align__(16) unsigned short s_un[4 * 480 * 8];     // 30720 B
    const int tid = threadIdx.x, nl = blockIdx.x;
    const int lane = tid & 63, wave = tid >> 6;
    const int n = lane & 15, q = lane >> 4;
    unsigned short* pa = s_un;           // [79][70]: pa[r][c] = img[r-2][c-1]
    unsigned short* pb = s_un + 5534;    // [79][70]: pb[r][c] = img[r-2][c-2]

    {
        unsigned* z32 = (unsigned*)s_un;
        for (int i = tid; i < 5532; i += 512) z32[i] = 0u;
        uint4 z4; z4.x = z4.y = z4.z = z4.w = 0u;
        for (int pc = tid; pc < 324; pc += 512) {
            int row, colc;
            if (pc < 180) { row = pc / 36; colc = pc % 36; if (row >= 2) row += 36; }
            else { int pz = pc - 180; row = 2 + (pz >> 2); colc = (pz & 3) ? 32 + (pz & 3) : 0; }
            int cc = row * 36 + colc;
            *(uint4*)(s_out1 + cc * 8) = z4;             // plane 0
            *(uint4*)(s_out1 + 11808 + cc * 8) = z4;     // plane 1
        }
    }
    __syncthreads();
    {
        const float4* src = (const float4*)(x + (size_t)nl * 4608);
        for (int i = tid; i < 1152; i += 512) {
            float4 val = src[i];
            int f = i * 4, row = (f >> 6) + 2, c = (f & 63) + 1;   // c odd
            unsigned short h0 = f2bf(val.x), h1 = f2bf(val.y);
            unsigned short h2 = f2bf(val.z), h3 = f2bf(val.w);
            unsigned short* ap = pa + row * 70 + c;
            ap[0] = h0; ap[1] = h1; ap[2] = h2; ap[3] = h3;
            unsigned* bp = (unsigned*)(pb + row * 70 + c + 1);     // even idx
            bp[0] = (unsigned)h0 | ((unsigned)h1 << 16);
            bp[1] = (unsigned)h2 | ((unsigned)h3 << 16);
        }
    }
    const float sc1 = g1[n] * rsqrtf(v1[n] + BN_EPS);
    const float bb1 = c1b[n];
    const float mm1 = b1[n] - m1[n] * sc1;
    const short8 bfr1 = *(const short8*)(wT1 + n * 32 + q * 8);
    __syncthreads();

    // phase A: conv1 (8 waves x 36 iters = 288 tiles)
    for (int i = 0; i < 36; ++i) {
        int t = wave * 36 + i;
        int pooled = 4 * t + (n >> 2);
        int ph = pooled >> 5, pw = pooled & 31;
        int py = (n >> 1) & 1, px = n & 1;
        int oh = 2 * ph + py, ow = 2 * pw + px;
        int r0 = (oh + 2 * q) * 70;
        const unsigned* base = px ? (const unsigned*)(pb + r0 + ow + 1)
                                  : (const unsigned*)(pa + r0 + ow);
        uint4 uu;
        uu.x = base[0];  uu.y = base[1];
        uu.z = base[35]; uu.w = base[36];
        short8 afr = *reinterpret_cast<short8*>(&uu);
        f32x4 acc = (f32x4){0.f, 0.f, 0.f, 0.f};
        acc = __builtin_amdgcn_mfma_f32_16x16x32_bf16(afr, bfr1, acc, 0, 0, 0);
        int po = 4 * t + q, oph = po >> 5, opw = po & 31;
        float mx = fmaxf(fmaxf(acc[0], acc[1]), fmaxf(acc[2], acc[3]));
        float val = fmaxf(mx + bb1, 0.f) * sc1 + mm1;
        int cc = (oph + 2) * 36 + (opw + 1);
        s_out1[(n >> 3) * 11808 + cc * 8 + (n & 7)] = f2bf(val);
    }
    __syncthreads();
    {
        uint4 z4; z4.x = z4.y = z4.z = z4.w = 0u;
        for (int pc = tid; pc < 192; pc += 512) {
            int row, colc;
            if (pc < 120) { row = pc / 20; colc = pc % 20; if (row >= 2) row += 18; }
            else { int pz = pc - 120; row = 2 + (pz >> 2); colc = (pz & 3) ? 16 + (pz & 3) : 0; }
            int cc = row * 20 + colc;
            *(uint4*)(s_un + cc * 8) = z4;
            *(uint4*)(s_un + 3840 + cc * 8) = z4;
            *(uint4*)(s_un + 7680 + cc * 8) = z4;
            *(uint4*)(s_un + 11520 + cc * 8) = z4;
        }
    }
    float bnb2[2], bns2[2], bnm2[2];
#pragma unroll
    for (int nt = 0; nt < 2; ++nt) {
        int oc = nt * 16 + n;
        float sc = g2[oc] * rsqrtf(v2[oc] + BN_EPS);
        bnb2[nt] = c2b[oc]; bns2[nt] = sc; bnm2[nt] = b2[oc] - m2[oc] * sc;
    }
    __syncthreads();

    // phase B: conv2 (36 tiles over 8 waves); reads base+immediate only
    for (int pp = wave; pp < 36; pp += 8) {
        int ph = pp >> 1, half = pp & 1;
        const unsigned short* bB = s_out1 + (q & 1) * 11808 + (q >> 1) * 8
                                   + (half * 16 + n) * 8 + (2 * ph) * 288;
        f32x4 acc[2][2];
#pragma unroll
        for (int ab = 0; ab < 2; ++ab)
#pragma unroll
            for (int nt = 0; nt < 2; ++nt) acc[ab][nt] = (f32x4){0.f, 0.f, 0.f, 0.f};
#pragma unroll
        for (int ky = 0; ky < 6; ++ky)
#pragma unroll
            for (int kxp = 0; kxp < 2; ++kxp) {
                int kk = ky * 2 + kxp;
                short8 w0 = *(const short8*)(wT2 + ((size_t)(kk * 32 + n) * 32) + q * 8);
                short8 w1 = *(const short8*)(wT2 + ((size_t)(kk * 32 + 16 + n) * 32) + q * 8);
#pragma unroll
                for (int ab = 0; ab < 2; ++ab) {
                    short8 afr = *(const short8*)(bB + ((ab + ky) * 288 + kxp * 16));
                    acc[ab][0] = __builtin_amdgcn_mfma_f32_16x16x32_bf16(afr, w0, acc[ab][0], 0, 0, 0);
                    acc[ab][1] = __builtin_amdgcn_mfma_f32_16x16x32_bf16(afr, w1, acc[ab][1], 0, 0, 0);
                }
            }
        int pw0 = half * 8 + q * 2;
#pragma unroll
        for (int nt = 0; nt < 2; ++nt) {
            int oc = nt * 16 + n;
            float p0 = fmaxf(fmaxf(acc[0][nt][0], acc[0][nt][1]),
                             fmaxf(acc[1][nt][0], acc[1][nt][1]));
            float p1 = fmaxf(fmaxf(acc[0][nt][2], acc[0][nt][3]),
                             fmaxf(acc[1][nt][2], acc[1][nt][3]));
            p0 = fmaxf(p0 + bnb2[nt], 0.f) * bns2[nt] + bnm2[nt];
            p1 = fmaxf(p1 + bnb2[nt], 0.f) * bns2[nt] + bnm2[nt];
            int cellA = (ph + 2) * 20 + pw0 + 1;
            int pl = (oc >> 3) * 3840, cl = oc & 7;
            s_un[pl + cellA * 8 + cl] = f2bf(p0);
            s_un[pl + (cellA + 1) * 8 + cl] = f2bf(p1);
        }
    }
    __syncthreads();

    // phase C: conv3 (12 tiles over 8 waves); reads base+immediate only
    for (int ch = wave; ch < 12; ch += 8) {
        int pr = ch >> 1, nth = ch & 1;
        const unsigned short* bC = s_un + q * 3840 + n * 8 + (3 * pr) * 160;
        f32x4 acc[3][2];
#pragma unroll
        for (int r = 0; r < 3; ++r)
#pragma unroll
            for (int t2 = 0; t2 < 2; ++t2) acc[r][t2] = (f32x4){0.f, 0.f, 0.f, 0.f};
#pragma unroll
        for (int ky = 0; ky < 6; ++ky)
#pragma unroll
            for (int kx = 0; kx < 4; ++kx) {
                int kk = ky * 4 + kx;
                short8 w0 = *(const short8*)(wT3 + ((size_t)(kk * 64 + nth * 32 + n) * 32) + q * 8);
                short8 w1 = *(const short8*)(wT3 + ((size_t)(kk * 64 + nth * 32 + 16 + n) * 32) + q * 8);
#pragma unroll
                for (int r = 0; r < 3; ++r) {
                    short8 afr = *(const short8*)(bC + ((r + ky) * 160 + kx * 8));
                    acc[r][0] = __builtin_amdgcn_mfma_f32_16x16x32_bf16(afr, w0, acc[r][0], 0, 0, 0);
                    acc[r][1] = __builtin_amdgcn_mfma_f32_16x16x32_bf16(afr, w1, acc[r][1], 0, 0, 0);
                }
            }
        size_t ob = (size_t)nl * 1536;
#pragma unroll
        for (int t2 = 0; t2 < 2; ++t2) {
            int oc = nth * 32 + t2 * 16 + n;
            float sc = g3[oc] * rsqrtf(v3[oc] + BN_EPS);
            float mx = -3.4e38f;
#pragma unroll
            for (int r = 0; r < 3; ++r)
#pragma unroll
                for (int e = 0; e < 4; ++e) mx = fmaxf(mx, acc[r][t2][e]);
            float val = fmaxf(mx + c3b[oc], 0.f) * sc + (b3[oc] - m3[oc] * sc);
            out3[ob + (size_t)oc * 24 + pr * 4 + q] = f2bf(val);
        }
    }
}

// ---- fc (MFMA, LDS-free, wide grid; prefetch + dual acc; f32 W in-reg cast)
__global__ __launch_bounds__(256) void fc_m(
    const unsigned short* __restrict__ A, const float* __restrict__ W,
    const float* __restrict__ bias, const float* __restrict__ g,
    const float* __restrict__ bt, const float* __restrict__ m,
    const float* __restrict__ v, unsigned short* __restrict__ out_b,
    float* __restrict__ out_f, int K, int N, int mode)   // mode 0=bf16, 1=f32
{
    const int tid = threadIdx.x;
    const int lane = tid & 63, wave = tid >> 6;
    const int n = lane & 15, q = lane >> 4;
    const int wr = wave >> 1, wc = wave & 1;
    const int r0 = blockIdx.y * 32 + wr * 16;
    const int c0 = blockIdx.x * 32 + wc * 16;
    const int col = c0 + n;

    float sc = g[col] * rsqrtf(v[col] + BN_EPS);
    float bb = bias[col];
    float mm = bt[col] - m[col] * sc;

    const unsigned short* Ap = A + (size_t)(r0 + n) * K + q * 8;
    const float* Bp = W + (size_t)col * K + q * 8;

    f32x4 acc0 = (f32x4){0.f, 0.f, 0.f, 0.f};
    f32x4 acc1 = (f32x4){0.f, 0.f, 0.f, 0.f};
    short8 a0 = *(const short8*)(Ap);
    short8 a1 = *(const short8*)(Ap + 32);
    short8 b0 = f2bf8(*(const float4*)(Bp), *(const float4*)(Bp + 4));
    short8 b1 = f2bf8(*(const float4*)(Bp + 32), *(const float4*)(Bp + 36));
#pragma unroll 2
    for (int kk = 64; kk < K; kk += 64) {
        short8 a0n = *(const short8*)(Ap + kk);
        short8 a1n = *(const short8*)(Ap + kk + 32);
        float4 c0a = *(const float4*)(Bp + kk);
        float4 c0b = *(const float4*)(Bp + kk + 4);
        float4 c1a = *(const float4*)(Bp + kk + 32);
        float4 c1b = *(const float4*)(Bp + kk + 36);
        acc0 = __builtin_amdgcn_mfma_f32_16x16x32_bf16(a0, b0, acc0, 0, 0, 0);
        acc1 = __builtin_amdgcn_mfma_f32_16x16x32_bf16(a1, b1, acc1, 0, 0, 0);
        a0 = a0n; a1 = a1n;
        b0 = f2bf8(c0a, c0b); b1 = f2bf8(c1a, c1b);
    }
    acc0 = __builtin_amdgcn_mfma_f32_16x16x32_bf16(a0, b0, acc0, 0, 0, 0);
    acc1 = __builtin_amdgcn_mfma_f32_16x16x32_bf16(a1, b1, acc1, 0, 0, 0);
#pragma unroll
    for (int e = 0; e < 4; ++e) {
        int row = r0 + q * 4 + e;
        float val = fmaxf(acc0[e] + acc1[e] + bb, 0.f) * sc + mm;
        if (mode == 0) out_b[(size_t)row * N + col] = f2bf(val);
        else           out_f[(size_t)row * N + col] = val;
    }
}

// ---- row L2-normalize; emit sq = sum(e^2) ---------------------------------
__global__ __launch_bounds__(128) void norm_k(const float* __restrict__ f3,
                                              float* __restrict__ E,
                                              float* __restrict__ sq)
{
    __shared__ float red[2];
    const int row = blockIdx.x, tid = threadIdx.x;
    float vv = f3[row * 128 + tid];
    float s = vv * vv;
#pragma unroll
    for (int off = 32; off >= 1; off >>= 1) s += __shfl_down(s, off, 64);
    if ((tid & 63) == 0) red[tid >> 6] = s;
    __syncthreads();
    float total = red[0] + red[1];
    float nn = fmaxf(sqrtf(total), 1e-12f);
    E[row * 128 + tid] = vv / nn;
    if (tid == 0) sq[row] = total / (nn * nn);
}

// ---- pairwise distance + global max ---------------------------------------
__global__ __launch_bounds__(256) void dist_k(const float* __restrict__ E,
                                              const float* __restrict__ sq,
                                              float* __restrict__ D,
                                              unsigned* __restrict__ mxslot)
{
    __shared__ __align__(16) float Ei[16 * 132];
    __shared__ __align__(16) float Ej[16 * 132];
    __shared__ float red[256];
    const int tid = threadIdx.x;
    const int bi = blockIdx.y * 16, bj = blockIdx.x * 16;
    {
        int lr = tid >> 4, lc = (tid & 15) * 8;
        float4 a0 = *(const float4*)(E + (bi + lr) * 128 + lc);
        float4 a1 = *(const float4*)(E + (bi + lr) * 128 + lc + 4);
        *(float4*)(Ei + lr * 132 + lc) = a0;
        *(float4*)(Ei + lr * 132 + lc + 4) = a1;
        float4 b0 = *(const float4*)(E + (bj + lr) * 128 + lc);
        float4 b1 = *(const float4*)(E + (bj + lr) * 128 + lc + 4);
        *(float4*)(Ej + lr * 132 + lc) = b0;
        *(float4*)(Ej + lr * 132 + lc + 4) = b1;
    }
    __syncthreads();
    const int tx = tid & 15, ty = tid >> 4;
    float dot = 0.f;
#pragma unroll 4
    for (int k = 0; k < 128; k += 4) {
        float4 a = *(const float4*)(Ei + ty * 132 + k);
        float4 b = *(const float4*)(Ej + tx * 132 + k);
        dot = fmaf(a.x, b.x, dot); dot = fmaf(a.y, b.y, dot);
        dot = fmaf(a.z, b.z, dot); dot = fmaf(a.w, b.w, dot);
    }
    int i = bi + ty, j = bj + tx;
    float d2 = sq[i] + sq[j] - 2.f * dot;
    float dist = sqrtf(fmaxf(d2, 1e-12f));
    dist = (d2 > 0.f) ? dist : 0.f;
    if (i == j) dist = 0.f;
    D[i * 512 + j] = dist;
    red[tid] = dist;
    __syncthreads();
    for (int s2 = 128; s2 > 0; s2 >>= 1) {
        if (tid < s2) red[tid] = fmaxf(red[tid], red[tid + s2]);
        __syncthreads();
    }
    if (tid == 0) atomicMax(mxslot, __float_as_uint(red[0]));
}

__global__ __launch_bounds__(256) void scale_k(float* __restrict__ D,
                                               const unsigned* __restrict__ mxslot)
{
    int idx = blockIdx.x * 256 + threadIdx.x;
    float M = __uint_as_float(*mxslot);
    D[idx] = D[idx] / M;
}

// ---------------------------------------------------------------------------
extern "C" void kernel_launch(void* const* d_in, const int* in_sizes, int n_in,
                              void* d_out, int out_size, void* d_ws, size_t ws_size,
                              hipStream_t stream)
{
    (void)in_sizes; (void)n_in; (void)out_size; (void)ws_size;
    const float* x    = (const float*)d_in[0];
    const float* c1w  = (const float*)d_in[1];
    const float* c1b  = (const float*)d_in[2];
    const float* g1   = (const float*)d_in[3];
    const float* b1   = (const float*)d_in[4];
    const float* m1   = (const float*)d_in[5];
    const float* v1   = (const float*)d_in[6];
    const float* c2w  = (const float*)d_in[7];
    const float* c2b  = (const float*)d_in[8];
    const float* g2   = (const float*)d_in[9];
    const float* b2   = (const float*)d_in[10];
    const float* m2   = (const float*)d_in[11];
    const float* v2   = (const float*)d_in[12];
    const float* c3w  = (const float*)d_in[13];
    const float* c3b  = (const float*)d_in[14];
    const float* g3   = (const float*)d_in[15];
    const float* b3   = (const float*)d_in[16];
    const float* m3   = (const float*)d_in[17];
    const float* v3   = (const float*)d_in[18];
    const float* fw1  = (const float*)d_in[19];
    const float* fb1  = (const float*)d_in[20];
    const float* gf1  = (const float*)d_in[21];
    const float* bf1  = (const float*)d_in[22];
    const float* mf1  = (const float*)d_in[23];
    const float* vf1  = (const float*)d_in[24];
    const float* fw2  = (const float*)d_in[25];
    const float* fb2  = (const float*)d_in[26];
    const float* gf2  = (const float*)d_in[27];
    const float* bf2  = (const float*)d_in[28];
    const float* mf2  = (const float*)d_in[29];
    const float* vf2  = (const float*)d_in[30];
    const float* fw3  = (const float*)d_in[31];
    const float* fb3  = (const float*)d_in[32];
    const float* gf3  = (const float*)d_in[33];
    const float* bf3  = (const float*)d_in[34];
    const float* mf3  = (const float*)d_in[35];
    const float* vf3  = (const float*)d_in[36];

    float* ws = (float*)d_ws;
    // ---- ws layout (float offsets, 16B-aligned) ---------------------------
    float* E    = ws + 0;                                    // 65536
    float* sq   = ws + 65536;                                // 512
    float* f3v  = ws + 66048;                                // 65536
    unsigned* mx = (unsigned*)(ws + 131584);
    unsigned short* wT1b = (unsigned short*)(ws + 131600);   // 512 ush
    unsigned short* wT2b = (unsigned short*)(ws + 131856);   // 12288 ush
    unsigned short* wT3b = (unsigned short*)(ws + 138000);   // 49152 ush
    unsigned short* out3b= (unsigned short*)(ws + 637712);   // 786432 ush
    unsigned short* a1b  = (unsigned short*)(ws + 1030928);  // 262144 ush
    unsigned short* a2b  = (unsigned short*)(ws + 1162000);  // 131072 ush

    float* out = (float*)d_out;

    repack_k<<<192, 256, 0, stream>>>(c1w, c2w, c3w, wT1b, wT2b, wT3b, mx);
    conv_all<<<512, 512, 0, stream>>>(x, wT1b, wT2b, wT3b,
                                      c1b, g1, b1, m1, v1,
                                      c2b, g2, b2, m2, v2,
                                      c3b, g3, b3, m3, v3, out3b);
    fc_m<<<dim3(16, 16), 256, 0, stream>>>(out3b, fw1, fb1, gf1, bf1, mf1, vf1,
                                           a1b, nullptr, 1536, 512, 0);
    fc_m<<<dim3(8, 16), 256, 0, stream>>>(a1b, fw2, fb2, gf2, bf2, mf2, vf2,
                                          a2b, nullptr, 512, 256, 0);
    fc_m<<<dim3(4, 16), 256, 0, stream>>>(a2b, fw3, fb3, gf3, bf3, mf3, vf3,
                                          nullptr, f3v, 256, 128, 1);
    norm_k<<<512, 128, 0, stream>>>(f3v, E, sq);
    dist_k<<<dim3(32, 32), 256, 0, stream>>>(E, sq, out, mx);
    scale_k<<<1024, 256, 0, stream>>>(out, mx);
}

// Round 8
// 214.169 us; speedup vs baseline: 1.3167x; 1.0219x over previous
//
#include <hip/hip_runtime.h>
#include <math.h>

// ---------------------------------------------------------------------------
// Round 17: cross-round ledger (R11/R14/R16 "others" = 162/172/173.5) shows:
//   full SCALAR repack = +10us (786K scalar loads + 2B stores);
//   fc in-register f32->bf16 cast = +11.5us (16 f2bf on the K-loop
//   critical path + 2x W bytes).
// Take the best cell: VECTORIZED FC cast in repack_k (float4x2 -> short8,
// 8 elems/thread, 464 blocks ~ 2us) + fc_m reads bf16 (R14-proven exact).
// scale_k vectorized float4. conv_all EXACTLY R14 (45.4us). 8 dispatches.
// ---------------------------------------------------------------------------

#define BN_EPS 1e-5f

typedef __attribute__((ext_vector_type(8))) short short8;   // 8 bf16 = 4 VGPR
typedef __attribute__((ext_vector_type(4))) float f32x4;

__device__ __forceinline__ unsigned short f2bf(float f) {
    unsigned u = __float_as_uint(f);
    u += 0x7fffu + ((u >> 16) & 1u);          // round-to-nearest-even
    return (unsigned short)(u >> 16);
}

__device__ __forceinline__ short8 f2bf8(float4 lo, float4 hi) {
    short8 r;
    r[0] = (short)f2bf(lo.x); r[1] = (short)f2bf(lo.y);
    r[2] = (short)f2bf(lo.z); r[3] = (short)f2bf(lo.w);
    r[4] = (short)f2bf(hi.x); r[5] = (short)f2bf(hi.y);
    r[6] = (short)f2bf(hi.z); r[7] = (short)f2bf(hi.w);
    return r;
}

// ---- weight repack: conv (scalar, tiny) + FC (vectorized 8/thread) ---------
__global__ __launch_bounds__(256) void repack_k(
    const float* __restrict__ w1, const float* __restrict__ w2,
    const float* __restrict__ w3,
    const float* __restrict__ fw1, const float* __restrict__ fw2,
    const float* __restrict__ fw3,
    unsigned short* __restrict__ wT1b,
    unsigned short* __restrict__ wT2b, unsigned short* __restrict__ wT3b,
    unsigned short* __restrict__ fw1b, unsigned short* __restrict__ fw2b,
    unsigned short* __restrict__ fw3b, unsigned* __restrict__ mxslot)
{
    int t = blockIdx.x * 256 + threadIdx.x;
    if (t == 0) *mxslot = 0u;
    if (t < 512) {
        int k = t & 31, oc = t >> 5;
        wT1b[t] = (k < 24) ? f2bf(w1[oc * 24 + k]) : (unsigned short)0;
    }
    if (t < 12288) {
        int k = t & 31, oc = (t >> 5) & 31, kk = t >> 10;
        int ky = kk >> 1, kxp = kk & 1;
        int hi = k >> 4, ic = k & 15;
        int kx = 2 * kxp + hi;
        wT2b[t] = f2bf(w2[((oc * 16 + ic) * 6 + ky) * 4 + kx]);
    }
    if (t < 49152) {
        int ic = t & 31, oc = (t >> 5) & 63, kk = t >> 11;
        int ky = kk >> 2, kx = kk & 3;
        wT3b[t] = f2bf(w3[((oc * 32 + ic) * 6 + ky) * 4 + kx]);
    }
    int base = t * 8;                       // FC cast: 950272 elems, 8/thread
    if (base < 950272) {
        const float* src; unsigned short* dst; int off;
        if (base < 786432)      { src = fw1; dst = fw1b; off = base; }
        else if (base < 917504) { src = fw2; dst = fw2b; off = base - 786432; }
        else                    { src = fw3; dst = fw3b; off = base - 917504; }
        float4 lo = *(const float4*)(src + off);
        float4 hi = *(const float4*)(src + off + 4);
        *(short8*)(dst + off) = f2bf8(lo, hi);
    }
}

// ---- conv_all: full conv stack, 1 block = 1 batch, 8 waves (R14, proven) ---
// s_out1 slot-major: plane p=ch>>3 in {0,1}; addr = p*11808 + cell*8 + (ch&7)
// s_un   slot-major: plane p=ch>>3 in {0..3}; addr = p*3840 + cell*8 + (ch&7)
// pa/pb row stride 70 ush; pb offset +4 ush (phase-A bank split).
__global__ __launch_bounds__(512) void conv_all(
    const float* __restrict__ x, const unsigned short* __restrict__ wT1,
    const unsigned short* __restrict__ wT2, const unsigned short* __restrict__ wT3,
    const float* __restrict__ c1b, const float* __restrict__ g1,
    const float* __restrict__ b1, const float* __restrict__ m1,
    const float* __restrict__ v1,
    const float* __restrict__ c2b, const float* __restrict__ g2,
    const float* __restrict__ b2, const float* __restrict__ m2,
    const float* __restrict__ v2,
    const float* __restrict__ c3b, const float* __restrict__ g3,
    const float* __restrict__ b3, const float* __restrict__ m3,
    const float* __restrict__ v3,
    unsigned short* __restrict__ out3)
{
    __shared__ __align__(16) unsigned short s_out1[2 * 1476 * 8];  // 47232 B
    __shared__ __align__(16) unsigned short s_un[4 * 480 * 8];     // 30720 B
    const int tid = threadIdx.x, nl = blockIdx.x;
    const int lane = tid & 63, wave = tid >> 6;
    const int n = lane & 15, q = lane >> 4;
    unsigned short* pa = s_un;           // [79][70]: pa[r][c] = img[r-2][c-1]
    unsigned short* pb = s_un + 5534;    // [79][70]: pb[r][c] = img[r-2][c-2]

    {
        unsigned* z32 = (unsigned*)s_un;
        for (int i = tid; i < 5532; i += 512) z32[i] = 0u;
        uint4 z4; z4.x = z4.y = z4.z = z4.w = 0u;
        for (int pc = tid; pc < 324; pc += 512) {
            int row, colc;
            if (pc < 180) { row = pc / 36; colc = pc % 36; if (row >= 2) row += 36; }
            else { int pz = pc - 180; row = 2 + (pz >> 2); colc = (pz & 3) ? 32 + (pz & 3) : 0; }
            int cc = row * 36 + colc;
            *(uint4*)(s_out1 + cc * 8) = z4;             // plane 0
            *(uint4*)(s_out1 + 11808 + cc * 8) = z4;     // plane 1
        }
    }
    __syncthreads();
    {
        const float4* src = (const float4*)(x + (size_t)nl * 4608);
        for (int i = tid; i < 1152; i += 512) {
            float4 val = src[i];
            int f = i * 4, row = (f >> 6) + 2, c = (f & 63) + 1;   // c odd
            unsigned short h0 = f2bf(val.x), h1 = f2bf(val.y);
            unsigned short h2 = f2bf(val.z), h3 = f2bf(val.w);
            unsigned short* ap = pa + row * 70 + c;
            ap[0] = h0; ap[1] = h1; ap[2] = h2; ap[3] = h3;
            unsigned* bp = (unsigned*)(pb + row * 70 + c + 1);     // even idx
            bp[0] = (unsigned)h0 | ((unsigned)h1 << 16);
            bp[1] = (unsigned)h2 | ((unsigned)h3 << 16);
        }
    }
    const float sc1 = g1[n] * rsqrtf(v1[n] + BN_EPS);
    const float bb1 = c1b[n];
    const float mm1 = b1[n] - m1[n] * sc1;
    const short8 bfr1 = *(const short8*)(wT1 + n * 32 + q * 8);
    __syncthreads();

    // phase A: conv1 (8 waves x 36 iters = 288 tiles)
    for (int i = 0; i < 36; ++i) {
        int t = wave * 36 + i;
        int pooled = 4 * t + (n >> 2);
        int ph = pooled >> 5, pw = pooled & 31;
        int py = (n >> 1) & 1, px = n & 1;
        int oh = 2 * ph + py, ow = 2 * pw + px;
        int r0 = (oh + 2 * q) * 70;
        const unsigned* base = px ? (const unsigned*)(pb + r0 + ow + 1)
                                  : (const unsigned*)(pa + r0 + ow);
        uint4 uu;
        uu.x = base[0];  uu.y = base[1];
        uu.z = base[35]; uu.w = base[36];
        short8 afr = *reinterpret_cast<short8*>(&uu);
        f32x4 acc = (f32x4){0.f, 0.f, 0.f, 0.f};
        acc = __builtin_amdgcn_mfma_f32_16x16x32_bf16(afr, bfr1, acc, 0, 0, 0);
        int po = 4 * t + q, oph = po >> 5, opw = po & 31;
        float mx = fmaxf(fmaxf(acc[0], acc[1]), fmaxf(acc[2], acc[3]));
        float val = fmaxf(mx + bb1, 0.f) * sc1 + mm1;
        int cc = (oph + 2) * 36 + (opw + 1);
        s_out1[(n >> 3) * 11808 + cc * 8 + (n & 7)] = f2bf(val);
    }
    __syncthreads();
    {
        uint4 z4; z4.x = z4.y = z4.z = z4.w = 0u;
        for (int pc = tid; pc < 192; pc += 512) {
            int row, colc;
            if (pc < 120) { row = pc / 20; colc = pc % 20; if (row >= 2) row += 18; }
            else { int pz = pc - 120; row = 2 + (pz >> 2); colc = (pz & 3) ? 16 + (pz & 3) : 0; }
            int cc = row * 20 + colc;
            *(uint4*)(s_un + cc * 8) = z4;
            *(uint4*)(s_un + 3840 + cc * 8) = z4;
            *(uint4*)(s_un + 7680 + cc * 8) = z4;
            *(uint4*)(s_un + 11520 + cc * 8) = z4;
        }
    }
    float bnb2[2], bns2[2], bnm2[2];
#pragma unroll
    for (int nt = 0; nt < 2; ++nt) {
        int oc = nt * 16 + n;
        float sc = g2[oc] * rsqrtf(v2[oc] + BN_EPS);
        bnb2[nt] = c2b[oc]; bns2[nt] = sc; bnm2[nt] = b2[oc] - m2[oc] * sc;
    }
    __syncthreads();

    // phase B: conv2 (36 tiles over 8 waves); reads base+immediate only
    for (int pp = wave; pp < 36; pp += 8) {
        int ph = pp >> 1, half = pp & 1;
        const unsigned short* bB = s_out1 + (q & 1) * 11808 + (q >> 1) * 8
                                   + (half * 16 + n) * 8 + (2 * ph) * 288;
        f32x4 acc[2][2];
#pragma unroll
        for (int ab = 0; ab < 2; ++ab)
#pragma unroll
            for (int nt = 0; nt < 2; ++nt) acc[ab][nt] = (f32x4){0.f, 0.f, 0.f, 0.f};
#pragma unroll
        for (int ky = 0; ky < 6; ++ky)
#pragma unroll
            for (int kxp = 0; kxp < 2; ++kxp) {
                int kk = ky * 2 + kxp;
                short8 w0 = *(const short8*)(wT2 + ((size_t)(kk * 32 + n) * 32) + q * 8);
                short8 w1 = *(const short8*)(wT2 + ((size_t)(kk * 32 + 16 + n) * 32) + q * 8);
#pragma unroll
                for (int ab = 0; ab < 2; ++ab) {
                    short8 afr = *(const short8*)(bB + ((ab + ky) * 288 + kxp * 16));
                    acc[ab][0] = __builtin_amdgcn_mfma_f32_16x16x32_bf16(afr, w0, acc[ab][0], 0, 0, 0);
                    acc[ab][1] = __builtin_amdgcn_mfma_f32_16x16x32_bf16(afr, w1, acc[ab][1], 0, 0, 0);
                }
            }
        int pw0 = half * 8 + q * 2;
#pragma unroll
        for (int nt = 0; nt < 2; ++nt) {
            int oc = nt * 16 + n;
            float p0 = fmaxf(fmaxf(acc[0][nt][0], acc[0][nt][1]),
                             fmaxf(acc[1][nt][0], acc[1][nt][1]));
            float p1 = fmaxf(fmaxf(acc[0][nt][2], acc[0][nt][3]),
                             fmaxf(acc[1][nt][2], acc[1][nt][3]));
            p0 = fmaxf(p0 + bnb2[nt], 0.f) * bns2[nt] + bnm2[nt];
            p1 = fmaxf(p1 + bnb2[nt], 0.f) * bns2[nt] + bnm2[nt];
            int cellA = (ph + 2) * 20 + pw0 + 1;
            int pl = (oc >> 3) * 3840, cl = oc & 7;
            s_un[pl + cellA * 8 + cl] = f2bf(p0);
            s_un[pl + (cellA + 1) * 8 + cl] = f2bf(p1);
        }
    }
    __syncthreads();

    // phase C: conv3 (12 tiles over 8 waves); reads base+immediate only
    for (int ch = wave; ch < 12; ch += 8) {
        int pr = ch >> 1, nth = ch & 1;
        const unsigned short* bC = s_un + q * 3840 + n * 8 + (3 * pr) * 160;
        f32x4 acc[3][2];
#pragma unroll
        for (int r = 0; r < 3; ++r)
#pragma unroll
            for (int t2 = 0; t2 < 2; ++t2) acc[r][t2] = (f32x4){0.f, 0.f, 0.f, 0.f};
#pragma unroll
        for (int ky = 0; ky < 6; ++ky)
#pragma unroll
            for (int kx = 0; kx < 4; ++kx) {
                int kk = ky * 4 + kx;
                short8 w0 = *(const short8*)(wT3 + ((size_t)(kk * 64 + nth * 32 + n) * 32) + q * 8);
                short8 w1 = *(const short8*)(wT3 + ((size_t)(kk * 64 + nth * 32 + 16 + n) * 32) + q * 8);
#pragma unroll
                for (int r = 0; r < 3; ++r) {
                    short8 afr = *(const short8*)(bC + ((r + ky) * 160 + kx * 8));
                    acc[r][0] = __builtin_amdgcn_mfma_f32_16x16x32_bf16(afr, w0, acc[r][0], 0, 0, 0);
                    acc[r][1] = __builtin_amdgcn_mfma_f32_16x16x32_bf16(afr, w1, acc[r][1], 0, 0, 0);
                }
            }
        size_t ob = (size_t)nl * 1536;
#pragma unroll
        for (int t2 = 0; t2 < 2; ++t2) {
            int oc = nth * 32 + t2 * 16 + n;
            float sc = g3[oc] * rsqrtf(v3[oc] + BN_EPS);
            float mx = -3.4e38f;
#pragma unroll
            for (int r = 0; r < 3; ++r)
#pragma unroll
                for (int e = 0; e < 4; ++e) mx = fmaxf(mx, acc[r][t2][e]);
            float val = fmaxf(mx + c3b[oc], 0.f) * sc + (b3[oc] - m3[oc] * sc);
            out3[ob + (size_t)oc * 24 + pr * 4 + q] = f2bf(val);
        }
    }
}

// ---- fc (MFMA, LDS-free, wide grid; prefetch + dual acc; bf16 W — R14) -----
__global__ __launch_bounds__(256) void fc_m(
    const unsigned short* __restrict__ A, const unsigned short* __restrict__ W,
    const float* __restrict__ bias, const float* __restrict__ g,
    const float* __restrict__ bt, const float* __restrict__ m,
    const float* __restrict__ v, unsigned short* __restrict__ out_b,
    float* __restrict__ out_f, int K, int N, int mode)   // mode 0=bf16, 1=f32
{
    const int tid = threadIdx.x;
    const int lane = tid & 63, wave = tid >> 6;
    const int n = lane & 15, q = lane >> 4;
    const int wr = wave >> 1, wc = wave & 1;
    const int r0 = blockIdx.y * 32 + wr * 16;
    const int c0 = blockIdx.x * 32 + wc * 16;
    const int col = c0 + n;

    float sc = g[col] * rsqrtf(v[col] + BN_EPS);
    float bb = bias[col];
    float mm = bt[col] - m[col] * sc;

    const unsigned short* Ap = A + (size_t)(r0 + n) * K + q * 8;
    const unsigned short* Bp = W + (size_t)col * K + q * 8;

    f32x4 acc0 = (f32x4){0.f, 0.f, 0.f, 0.f};
    f32x4 acc1 = (f32x4){0.f, 0.f, 0.f, 0.f};
    short8 a0 = *(const short8*)(Ap);
    short8 b0 = *(const short8*)(Bp);
    short8 a1 = *(const short8*)(Ap + 32);
    short8 b1 = *(const short8*)(Bp + 32);
#pragma unroll 2
    for (int kk = 64; kk < K; kk += 64) {
        short8 a0n = *(const short8*)(Ap + kk);
        short8 b0n = *(const short8*)(Bp + kk);
        short8 a1n = *(const short8*)(Ap + kk + 32);
        short8 b1n = *(const short8*)(Bp + kk + 32);
        acc0 = __builtin_amdgcn_mfma_f32_16x16x32_bf16(a0, b0, acc0, 0, 0, 0);
        acc1 = __builtin_amdgcn_mfma_f32_16x16x32_bf16(a1, b1, acc1, 0, 0, 0);
        a0 = a0n; b0 = b0n; a1 = a1n; b1 = b1n;
    }
    acc0 = __builtin_amdgcn_mfma_f32_16x16x32_bf16(a0, b0, acc0, 0, 0, 0);
    acc1 = __builtin_amdgcn_mfma_f32_16x16x32_bf16(a1, b1, acc1, 0, 0, 0);
#pragma unroll
    for (int e = 0; e < 4; ++e) {
        int row = r0 + q * 4 + e;
        float val = fmaxf(acc0[e] + acc1[e] + bb, 0.f) * sc + mm;
        if (mode == 0) out_b[(size_t)row * N + col] = f2bf(val);
        else           out_f[(size_t)row * N + col] = val;
    }
}

// ---- row L2-normalize; emit sq = sum(e^2) ---------------------------------
__global__ __launch_bounds__(128) void norm_k(const float* __restrict__ f3,
                                              float* __restrict__ E,
                                              float* __restrict__ sq)
{
    __shared__ float red[2];
    const int row = blockIdx.x, tid = threadIdx.x;
    float vv = f3[row * 128 + tid];
    float s = vv * vv;
#pragma unroll
    for (int off = 32; off >= 1; off >>= 1) s += __shfl_down(s, off, 64);
    if ((tid & 63) == 0) red[tid >> 6] = s;
    __syncthreads();
    float total = red[0] + red[1];
    float nn = fmaxf(sqrtf(total), 1e-12f);
    E[row * 128 + tid] = vv / nn;
    if (tid == 0) sq[row] = total / (nn * nn);
}

// ---- pairwise distance + global max ---------------------------------------
__global__ __launch_bounds__(256) void dist_k(const float* __restrict__ E,
                                              const float* __restrict__ sq,
                                              float* __restrict__ D,
                                              unsigned* __restrict__ mxslot)
{
    __shared__ __align__(16) float Ei[16 * 132];
    __shared__ __align__(16) float Ej[16 * 132];
    __shared__ float red[256];
    const int tid = threadIdx.x;
    const int bi = blockIdx.y * 16, bj = blockIdx.x * 16;
    {
        int lr = tid >> 4, lc = (tid & 15) * 8;
        float4 a0 = *(const float4*)(E + (bi + lr) * 128 + lc);
        float4 a1 = *(const float4*)(E + (bi + lr) * 128 + lc + 4);
        *(float4*)(Ei + lr * 132 + lc) = a0;
        *(float4*)(Ei + lr * 132 + lc + 4) = a1;
        float4 b0 = *(const float4*)(E + (bj + lr) * 128 + lc);
        float4 b1 = *(const float4*)(E + (bj + lr) * 128 + lc + 4);
        *(float4*)(Ej + lr * 132 + lc) = b0;
        *(float4*)(Ej + lr * 132 + lc + 4) = b1;
    }
    __syncthreads();
    const int tx = tid & 15, ty = tid >> 4;
    float dot = 0.f;
#pragma unroll 4
    for (int k = 0; k < 128; k += 4) {
        float4 a = *(const float4*)(Ei + ty * 132 + k);
        float4 b = *(const float4*)(Ej + tx * 132 + k);
        dot = fmaf(a.x, b.x, dot); dot = fmaf(a.y, b.y, dot);
        dot = fmaf(a.z, b.z, dot); dot = fmaf(a.w, b.w, dot);
    }
    int i = bi + ty, j = bj + tx;
    float d2 = sq[i] + sq[j] - 2.f * dot;
    float dist = sqrtf(fmaxf(d2, 1e-12f));
    dist = (d2 > 0.f) ? dist : 0.f;
    if (i == j) dist = 0.f;
    D[i * 512 + j] = dist;
    red[tid] = dist;
    __syncthreads();
    for (int s2 = 128; s2 > 0; s2 >>= 1) {
        if (tid < s2) red[tid] = fmaxf(red[tid], red[tid + s2]);
        __syncthreads();
    }
    if (tid == 0) atomicMax(mxslot, __float_as_uint(red[0]));
}

// ---- scale (vectorized float4) --------------------------------------------
__global__ __launch_bounds__(256) void scale_k(float* __restrict__ D,
                                               const unsigned* __restrict__ mxslot)
{
    int idx = (blockIdx.x * 256 + threadIdx.x) * 4;
    float M = __uint_as_float(*mxslot);
    float4 d = *(float4*)(D + idx);
    d.x /= M; d.y /= M; d.z /= M; d.w /= M;
    *(float4*)(D + idx) = d;
}

// ---------------------------------------------------------------------------
extern "C" void kernel_launch(void* const* d_in, const int* in_sizes, int n_in,
                              void* d_out, int out_size, void* d_ws, size_t ws_size,
                              hipStream_t stream)
{
    (void)in_sizes; (void)n_in; (void)out_size; (void)ws_size;
    const float* x    = (const float*)d_in[0];
    const float* c1w  = (const float*)d_in[1];
    const float* c1b  = (const float*)d_in[2];
    const float* g1   = (const float*)d_in[3];
    const float* b1   = (const float*)d_in[4];
    const float* m1   = (const float*)d_in[5];
    const float* v1   = (const float*)d_in[6];
    const float* c2w  = (const float*)d_in[7];
    const float* c2b  = (const float*)d_in[8];
    const float* g2   = (const float*)d_in[9];
    const float* b2   = (const float*)d_in[10];
    const float* m2   = (const float*)d_in[11];
    const float* v2   = (const float*)d_in[12];
    const float* c3w  = (const float*)d_in[13];
    const float* c3b  = (const float*)d_in[14];
    const float* g3   = (const float*)d_in[15];
    const float* b3   = (const float*)d_in[16];
    const float* m3   = (const float*)d_in[17];
    const float* v3   = (const float*)d_in[18];
    const float* fw1  = (const float*)d_in[19];
    const float* fb1  = (const float*)d_in[20];
    const float* gf1  = (const float*)d_in[21];
    const float* bf1  = (const float*)d_in[22];
    const float* mf1  = (const float*)d_in[23];
    const float* vf1  = (const float*)d_in[24];
    const float* fw2  = (const float*)d_in[25];
    const float* fb2  = (const float*)d_in[26];
    const float* gf2  = (const float*)d_in[27];
    const float* bf2  = (const float*)d_in[28];
    const float* mf2  = (const float*)d_in[29];
    const float* vf2  = (const float*)d_in[30];
    const float* fw3  = (const float*)d_in[31];
    const float* fb3  = (const float*)d_in[32];
    const float* gf3  = (const float*)d_in[33];
    const float* bf3  = (const float*)d_in[34];
    const float* mf3  = (const float*)d_in[35];
    const float* vf3  = (const float*)d_in[36];

    float* ws = (float*)d_ws;
    // ---- ws layout (float offsets, 16B-aligned) ---------------------------
    float* E    = ws + 0;                                    // 65536
    float* sq   = ws + 65536;                                // 512
    float* f3v  = ws + 66048;                                // 65536
    unsigned* mx = (unsigned*)(ws + 131584);
    unsigned short* wT1b = (unsigned short*)(ws + 131600);   // 512 ush
    unsigned short* wT2b = (unsigned short*)(ws + 131856);   // 12288 ush
    unsigned short* wT3b = (unsigned short*)(ws + 138000);   // 49152 ush
    unsigned short* fw1b = (unsigned short*)(ws + 162576);   // 786432 ush
    unsigned short* fw2b = (unsigned short*)(ws + 555792);   // 131072 ush
    unsigned short* fw3b = (unsigned short*)(ws + 621328);   // 32768 ush
    unsigned short* out3b= (unsigned short*)(ws + 637712);   // 786432 ush
    unsigned short* a1b  = (unsigned short*)(ws + 1030928);  // 262144 ush
    unsigned short* a2b  = (unsigned short*)(ws + 1162000);  // 131072 ush

    float* out = (float*)d_out;

    repack_k<<<464, 256, 0, stream>>>(c1w, c2w, c3w, fw1, fw2, fw3,
                                      wT1b, wT2b, wT3b, fw1b, fw2b, fw3b, mx);
    conv_all<<<512, 512, 0, stream>>>(x, wT1b, wT2b, wT3b,
                                      c1b, g1, b1, m1, v1,
                                      c2b, g2, b2, m2, v2,
                                      c3b, g3, b3, m3, v3, out3b);
    fc_m<<<dim3(16, 16), 256, 0, stream>>>(out3b, fw1b, fb1, gf1, bf1, mf1, vf1,
                                           a1b, nullptr, 1536, 512, 0);
    fc_m<<<dim3(8, 16), 256, 0, stream>>>(a1b, fw2b, fb2, gf2, bf2, mf2, vf2,
                                          a2b, nullptr, 512, 256, 0);
    fc_m<<<dim3(4, 16), 256, 0, stream>>>(a2b, fw3b, fb3, gf3, bf3, mf3, vf3,
                                          nullptr, f3v, 256, 128, 1);
    norm_k<<<512, 128, 0, stream>>>(f3v, E, sq);
    dist_k<<<dim3(32, 32), 256, 0, stream>>>(E, sq, out, mx);
    scale_k<<<256, 256, 0, stream>>>(out, mx);
}

// Round 9
// 209.453 us; speedup vs baseline: 1.3463x; 1.0225x over previous
//
#include <hip/hip_runtime.h>
#include <math.h>

// ---------------------------------------------------------------------------
// Round 18: ledger isolates the fc stack at ~110-125us (2.5x conv_all!).
// Mechanism: fc_m = 1 wave/SIMD (fc1: 256 blocks), half/quarter GPU idle
// (fc2: 128, fc3: 64 blocks); serial 24-iter K-loop exposed to full L2/HBM
// latency with zero TLP. (R8 note corroborates: 32-block FC = 85us @ 1.3%
// occupancy.)
// Fix: fc_ks = K-split FC. 16x16 tile/block, 4 waves split K 4-ways, LDS
// partial reduce (4KB), wave-0 epilogue. fc1: 1024 blk x 6 iters; fc2: 512
// blk x 2; fc3: 256 blk x 1. 4x waves, 4x shorter critical path, all CUs
// busy. conv_all / repack / norm / dist / scale EXACTLY R17.
// ---------------------------------------------------------------------------

#define BN_EPS 1e-5f

typedef __attribute__((ext_vector_type(8))) short short8;   // 8 bf16 = 4 VGPR
typedef __attribute__((ext_vector_type(4))) float f32x4;

__device__ __forceinline__ unsigned short f2bf(float f) {
    unsigned u = __float_as_uint(f);
    u += 0x7fffu + ((u >> 16) & 1u);          // round-to-nearest-even
    return (unsigned short)(u >> 16);
}

__device__ __forceinline__ short8 f2bf8(float4 lo, float4 hi) {
    short8 r;
    r[0] = (short)f2bf(lo.x); r[1] = (short)f2bf(lo.y);
    r[2] = (short)f2bf(lo.z); r[3] = (short)f2bf(lo.w);
    r[4] = (short)f2bf(hi.x); r[5] = (short)f2bf(hi.y);
    r[6] = (short)f2bf(hi.z); r[7] = (short)f2bf(hi.w);
    return r;
}

// ---- weight repack: conv (scalar, tiny) + FC (vectorized 8/thread) ---------
__global__ __launch_bounds__(256) void repack_k(
    const float* __restrict__ w1, const float* __restrict__ w2,
    const float* __restrict__ w3,
    const float* __restrict__ fw1, const float* __restrict__ fw2,
    const float* __restrict__ fw3,
    unsigned short* __restrict__ wT1b,
    unsigned short* __restrict__ wT2b, unsigned short* __restrict__ wT3b,
    unsigned short* __restrict__ fw1b, unsigned short* __restrict__ fw2b,
    unsigned short* __restrict__ fw3b, unsigned* __restrict__ mxslot)
{
    int t = blockIdx.x * 256 + threadIdx.x;
    if (t == 0) *mxslot = 0u;
    if (t < 512) {
        int k = t & 31, oc = t >> 5;
        wT1b[t] = (k < 24) ? f2bf(w1[oc * 24 + k]) : (unsigned short)0;
    }
    if (t < 12288) {
        int k = t & 31, oc = (t >> 5) & 31, kk = t >> 10;
        int ky = kk >> 1, kxp = kk & 1;
        int hi = k >> 4, ic = k & 15;
        int kx = 2 * kxp + hi;
        wT2b[t] = f2bf(w2[((oc * 16 + ic) * 6 + ky) * 4 + kx]);
    }
    if (t < 49152) {
        int ic = t & 31, oc = (t >> 5) & 63, kk = t >> 11;
        int ky = kk >> 2, kx = kk & 3;
        wT3b[t] = f2bf(w3[((oc * 32 + ic) * 6 + ky) * 4 + kx]);
    }
    int base = t * 8;                       // FC cast: 950272 elems, 8/thread
    if (base < 950272) {
        const float* src; unsigned short* dst; int off;
        if (base < 786432)      { src = fw1; dst = fw1b; off = base; }
        else if (base < 917504) { src = fw2; dst = fw2b; off = base - 786432; }
        else                    { src = fw3; dst = fw3b; off = base - 917504; }
        float4 lo = *(const float4*)(src + off);
        float4 hi = *(const float4*)(src + off + 4);
        *(short8*)(dst + off) = f2bf8(lo, hi);
    }
}

// ---- conv_all: full conv stack, 1 block = 1 batch, 8 waves (R14, proven) ---
// s_out1 slot-major: plane p=ch>>3 in {0,1}; addr = p*11808 + cell*8 + (ch&7)
// s_un   slot-major: plane p=ch>>3 in {0..3}; addr = p*3840 + cell*8 + (ch&7)
// pa/pb row stride 70 ush; pb offset +4 ush (phase-A bank split).
__global__ __launch_bounds__(512) void conv_all(
    const float* __restrict__ x, const unsigned short* __restrict__ wT1,
    const unsigned short* __restrict__ wT2, const unsigned short* __restrict__ wT3,
    const float* __restrict__ c1b, const float* __restrict__ g1,
    const float* __restrict__ b1, const float* __restrict__ m1,
    const float* __restrict__ v1,
    const float* __restrict__ c2b, const float* __restrict__ g2,
    const float* __restrict__ b2, const float* __restrict__ m2,
    const float* __restrict__ v2,
    const float* __restrict__ c3b, const float* __restrict__ g3,
    const float* __restrict__ b3, const float* __restrict__ m3,
    const float* __restrict__ v3,
    unsigned short* __restrict__ out3)
{
    __shared__ __align__(16) unsigned short s_out1[2 * 1476 * 8];  // 47232 B
    __shared__ __align__(16) unsigned short s_un[4 * 480 * 8];     // 30720 B
    const int tid = threadIdx.x, nl = blockIdx.x;
    const int lane = tid & 63, wave = tid >> 6;
    const int n = lane & 15, q = lane >> 4;
    unsigned short* pa = s_un;           // [79][70]: pa[r][c] = img[r-2][c-1]
    unsigned short* pb = s_un + 5534;    // [79][70]: pb[r][c] = img[r-2][c-2]

    {
        unsigned* z32 = (unsigned*)s_un;
        for (int i = tid; i < 5532; i += 512) z32[i] = 0u;
        uint4 z4; z4.x = z4.y = z4.z = z4.w = 0u;
        for (int pc = tid; pc < 324; pc += 512) {
            int row, colc;
            if (pc < 180) { row = pc / 36; colc = pc % 36; if (row >= 2) row += 36; }
            else { int pz = pc - 180; row = 2 + (pz >> 2); colc = (pz & 3) ? 32 + (pz & 3) : 0; }
            int cc = row * 36 + colc;
            *(uint4*)(s_out1 + cc * 8) = z4;             // plane 0
            *(uint4*)(s_out1 + 11808 + cc * 8) = z4;     // plane 1
        }
    }
    __syncthreads();
    {
        const float4* src = (const float4*)(x + (size_t)nl * 4608);
        for (int i = tid; i < 1152; i += 512) {
            float4 val = src[i];
            int f = i * 4, row = (f >> 6) + 2, c = (f & 63) + 1;   // c odd
            unsigned short h0 = f2bf(val.x), h1 = f2bf(val.y);
            unsigned short h2 = f2bf(val.z), h3 = f2bf(val.w);
            unsigned short* ap = pa + row * 70 + c;
            ap[0] = h0; ap[1] = h1; ap[2] = h2; ap[3] = h3;
            unsigned* bp = (unsigned*)(pb + row * 70 + c + 1);     // even idx
            bp[0] = (unsigned)h0 | ((unsigned)h1 << 16);
            bp[1] = (unsigned)h2 | ((unsigned)h3 << 16);
        }
    }
    const float sc1 = g1[n] * rsqrtf(v1[n] + BN_EPS);
    const float bb1 = c1b[n];
    const float mm1 = b1[n] - m1[n] * sc1;
    const short8 bfr1 = *(const short8*)(wT1 + n * 32 + q * 8);
    __syncthreads();

    // phase A: conv1 (8 waves x 36 iters = 288 tiles)
    for (int i = 0; i < 36; ++i) {
        int t = wave * 36 + i;
        int pooled = 4 * t + (n >> 2);
        int ph = pooled >> 5, pw = pooled & 31;
        int py = (n >> 1) & 1, px = n & 1;
        int oh = 2 * ph + py, ow = 2 * pw + px;
        int r0 = (oh + 2 * q) * 70;
        const unsigned* base = px ? (const unsigned*)(pb + r0 + ow + 1)
                                  : (const unsigned*)(pa + r0 + ow);
        uint4 uu;
        uu.x = base[0];  uu.y = base[1];
        uu.z = base[35]; uu.w = base[36];
        short8 afr = *reinterpret_cast<short8*>(&uu);
        f32x4 acc = (f32x4){0.f, 0.f, 0.f, 0.f};
        acc = __builtin_amdgcn_mfma_f32_16x16x32_bf16(afr, bfr1, acc, 0, 0, 0);
        int po = 4 * t + q, oph = po >> 5, opw = po & 31;
        float mx = fmaxf(fmaxf(acc[0], acc[1]), fmaxf(acc[2], acc[3]));
        float val = fmaxf(mx + bb1, 0.f) * sc1 + mm1;
        int cc = (oph + 2) * 36 + (opw + 1);
        s_out1[(n >> 3) * 11808 + cc * 8 + (n & 7)] = f2bf(val);
    }
    __syncthreads();
    {
        uint4 z4; z4.x = z4.y = z4.z = z4.w = 0u;
        for (int pc = tid; pc < 192; pc += 512) {
            int row, colc;
            if (pc < 120) { row = pc / 20; colc = pc % 20; if (row >= 2) row += 18; }
            else { int pz = pc - 120; row = 2 + (pz >> 2); colc = (pz & 3) ? 16 + (pz & 3) : 0; }
            int cc = row * 20 + colc;
            *(uint4*)(s_un + cc * 8) = z4;
            *(uint4*)(s_un + 3840 + cc * 8) = z4;
            *(uint4*)(s_un + 7680 + cc * 8) = z4;
            *(uint4*)(s_un + 11520 + cc * 8) = z4;
        }
    }
    float bnb2[2], bns2[2], bnm2[2];
#pragma unroll
    for (int nt = 0; nt < 2; ++nt) {
        int oc = nt * 16 + n;
        float sc = g2[oc] * rsqrtf(v2[oc] + BN_EPS);
        bnb2[nt] = c2b[oc]; bns2[nt] = sc; bnm2[nt] = b2[oc] - m2[oc] * sc;
    }
    __syncthreads();

    // phase B: conv2 (36 tiles over 8 waves); reads base+immediate only
    for (int pp = wave; pp < 36; pp += 8) {
        int ph = pp >> 1, half = pp & 1;
        const unsigned short* bB = s_out1 + (q & 1) * 11808 + (q >> 1) * 8
                                   + (half * 16 + n) * 8 + (2 * ph) * 288;
        f32x4 acc[2][2];
#pragma unroll
        for (int ab = 0; ab < 2; ++ab)
#pragma unroll
            for (int nt = 0; nt < 2; ++nt) acc[ab][nt] = (f32x4){0.f, 0.f, 0.f, 0.f};
#pragma unroll
        for (int ky = 0; ky < 6; ++ky)
#pragma unroll
            for (int kxp = 0; kxp < 2; ++kxp) {
                int kk = ky * 2 + kxp;
                short8 w0 = *(const short8*)(wT2 + ((size_t)(kk * 32 + n) * 32) + q * 8);
                short8 w1 = *(const short8*)(wT2 + ((size_t)(kk * 32 + 16 + n) * 32) + q * 8);
#pragma unroll
                for (int ab = 0; ab < 2; ++ab) {
                    short8 afr = *(const short8*)(bB + ((ab + ky) * 288 + kxp * 16));
                    acc[ab][0] = __builtin_amdgcn_mfma_f32_16x16x32_bf16(afr, w0, acc[ab][0], 0, 0, 0);
                    acc[ab][1] = __builtin_amdgcn_mfma_f32_16x16x32_bf16(afr, w1, acc[ab][1], 0, 0, 0);
                }
            }
        int pw0 = half * 8 + q * 2;
#pragma unroll
        for (int nt = 0; nt < 2; ++nt) {
            int oc = nt * 16 + n;
            float p0 = fmaxf(fmaxf(acc[0][nt][0], acc[0][nt][1]),
                             fmaxf(acc[1][nt][0], acc[1][nt][1]));
            float p1 = fmaxf(fmaxf(acc[0][nt][2], acc[0][nt][3]),
                             fmaxf(acc[1][nt][2], acc[1][nt][3]));
            p0 = fmaxf(p0 + bnb2[nt], 0.f) * bns2[nt] + bnm2[nt];
            p1 = fmaxf(p1 + bnb2[nt], 0.f) * bns2[nt] + bnm2[nt];
            int cellA = (ph + 2) * 20 + pw0 + 1;
            int pl = (oc >> 3) * 3840, cl = oc & 7;
            s_un[pl + cellA * 8 + cl] = f2bf(p0);
            s_un[pl + (cellA + 1) * 8 + cl] = f2bf(p1);
        }
    }
    __syncthreads();

    // phase C: conv3 (12 tiles over 8 waves); reads base+immediate only
    for (int ch = wave; ch < 12; ch += 8) {
        int pr = ch >> 1, nth = ch & 1;
        const unsigned short* bC = s_un + q * 3840 + n * 8 + (3 * pr) * 160;
        f32x4 acc[3][2];
#pragma unroll
        for (int r = 0; r < 3; ++r)
#pragma unroll
            for (int t2 = 0; t2 < 2; ++t2) acc[r][t2] = (f32x4){0.f, 0.f, 0.f, 0.f};
#pragma unroll
        for (int ky = 0; ky < 6; ++ky)
#pragma unroll
            for (int kx = 0; kx < 4; ++kx) {
                int kk = ky * 4 + kx;
                short8 w0 = *(const short8*)(wT3 + ((size_t)(kk * 64 + nth * 32 + n) * 32) + q * 8);
                short8 w1 = *(const short8*)(wT3 + ((size_t)(kk * 64 + nth * 32 + 16 + n) * 32) + q * 8);
#pragma unroll
                for (int r = 0; r < 3; ++r) {
                    short8 afr = *(const short8*)(bC + ((r + ky) * 160 + kx * 8));
                    acc[r][0] = __builtin_amdgcn_mfma_f32_16x16x32_bf16(afr, w0, acc[r][0], 0, 0, 0);
                    acc[r][1] = __builtin_amdgcn_mfma_f32_16x16x32_bf16(afr, w1, acc[r][1], 0, 0, 0);
                }
            }
        size_t ob = (size_t)nl * 1536;
#pragma unroll
        for (int t2 = 0; t2 < 2; ++t2) {
            int oc = nth * 32 + t2 * 16 + n;
            float sc = g3[oc] * rsqrtf(v3[oc] + BN_EPS);
            float mx = -3.4e38f;
#pragma unroll
            for (int r = 0; r < 3; ++r)
#pragma unroll
                for (int e = 0; e < 4; ++e) mx = fmaxf(mx, acc[r][t2][e]);
            float val = fmaxf(mx + c3b[oc], 0.f) * sc + (b3[oc] - m3[oc] * sc);
            out3[ob + (size_t)oc * 24 + pr * 4 + q] = f2bf(val);
        }
    }
}

// ---- fc_ks: K-split FC. 16x16 tile/block, 4 waves split K, LDS reduce ------
__global__ __launch_bounds__(256) void fc_ks(
    const unsigned short* __restrict__ A, const unsigned short* __restrict__ W,
    const float* __restrict__ bias, const float* __restrict__ g,
    const float* __restrict__ bt, const float* __restrict__ m,
    const float* __restrict__ v, unsigned short* __restrict__ out_b,
    float* __restrict__ out_f, int K, int N, int mode)   // mode 0=bf16, 1=f32
{
    __shared__ f32x4 part[256];                    // 4 KB partials
    const int tid = threadIdx.x;
    const int lane = tid & 63, wave = tid >> 6;
    const int n = lane & 15, q = lane >> 4;
    const int r0 = blockIdx.y * 16;
    const int c0 = blockIdx.x * 16;
    const int col = c0 + n;

    const int Kc = K >> 2;                         // per-wave K chunk
    const int base = wave * Kc;
    const unsigned short* Ap = A + (size_t)(r0 + n) * K + base + q * 8;
    const unsigned short* Bp = W + (size_t)col * K + base + q * 8;

    f32x4 acc0 = (f32x4){0.f, 0.f, 0.f, 0.f};
    f32x4 acc1 = (f32x4){0.f, 0.f, 0.f, 0.f};
#pragma unroll 2
    for (int kk = 0; kk < Kc; kk += 64) {
        short8 a0 = *(const short8*)(Ap + kk);
        short8 b0 = *(const short8*)(Bp + kk);
        short8 a1 = *(const short8*)(Ap + kk + 32);
        short8 b1 = *(const short8*)(Bp + kk + 32);
        acc0 = __builtin_amdgcn_mfma_f32_16x16x32_bf16(a0, b0, acc0, 0, 0, 0);
        acc1 = __builtin_amdgcn_mfma_f32_16x16x32_bf16(a1, b1, acc1, 0, 0, 0);
    }
    part[tid] = acc0 + acc1;
    __syncthreads();
    if (wave == 0) {
        f32x4 s = part[lane] + part[64 + lane] + part[128 + lane] + part[192 + lane];
        float sc = g[col] * rsqrtf(v[col] + BN_EPS);
        float bb = bias[col];
        float mm = bt[col] - m[col] * sc;
#pragma unroll
        for (int e = 0; e < 4; ++e) {
            int row = r0 + q * 4 + e;
            float val = fmaxf(s[e] + bb, 0.f) * sc + mm;
            if (mode == 0) out_b[(size_t)row * N + col] = f2bf(val);
            else           out_f[(size_t)row * N + col] = val;
        }
    }
}

// ---- row L2-normalize; emit sq = sum(e^2) ---------------------------------
__global__ __launch_bounds__(128) void norm_k(const float* __restrict__ f3,
                                              float* __restrict__ E,
                                              float* __restrict__ sq)
{
    __shared__ float red[2];
    const int row = blockIdx.x, tid = threadIdx.x;
    float vv = f3[row * 128 + tid];
    float s = vv * vv;
#pragma unroll
    for (int off = 32; off >= 1; off >>= 1) s += __shfl_down(s, off, 64);
    if ((tid & 63) == 0) red[tid >> 6] = s;
    __syncthreads();
    float total = red[0] + red[1];
    float nn = fmaxf(sqrtf(total), 1e-12f);
    E[row * 128 + tid] = vv / nn;
    if (tid == 0) sq[row] = total / (nn * nn);
}

// ---- pairwise distance + global max ---------------------------------------
__global__ __launch_bounds__(256) void dist_k(const float* __restrict__ E,
                                              const float* __restrict__ sq,
                                              float* __restrict__ D,
                                              unsigned* __restrict__ mxslot)
{
    __shared__ __align__(16) float Ei[16 * 132];
    __shared__ __align__(16) float Ej[16 * 132];
    __shared__ float red[256];
    const int tid = threadIdx.x;
    const int bi = blockIdx.y * 16, bj = blockIdx.x * 16;
    {
        int lr = tid >> 4, lc = (tid & 15) * 8;
        float4 a0 = *(const float4*)(E + (bi + lr) * 128 + lc);
        float4 a1 = *(const float4*)(E + (bi + lr) * 128 + lc + 4);
        *(float4*)(Ei + lr * 132 + lc) = a0;
        *(float4*)(Ei + lr * 132 + lc + 4) = a1;
        float4 b0 = *(const float4*)(E + (bj + lr) * 128 + lc);
        float4 b1 = *(const float4*)(E + (bj + lr) * 128 + lc + 4);
        *(float4*)(Ej + lr * 132 + lc) = b0;
        *(float4*)(Ej + lr * 132 + lc + 4) = b1;
    }
    __syncthreads();
    const int tx = tid & 15, ty = tid >> 4;
    float dot = 0.f;
#pragma unroll 4
    for (int k = 0; k < 128; k += 4) {
        float4 a = *(const float4*)(Ei + ty * 132 + k);
        float4 b = *(const float4*)(Ej + tx * 132 + k);
        dot = fmaf(a.x, b.x, dot); dot = fmaf(a.y, b.y, dot);
        dot = fmaf(a.z, b.z, dot); dot = fmaf(a.w, b.w, dot);
    }
    int i = bi + ty, j = bj + tx;
    float d2 = sq[i] + sq[j] - 2.f * dot;
    float dist = sqrtf(fmaxf(d2, 1e-12f));
    dist = (d2 > 0.f) ? dist : 0.f;
    if (i == j) dist = 0.f;
    D[i * 512 + j] = dist;
    red[tid] = dist;
    __syncthreads();
    for (int s2 = 128; s2 > 0; s2 >>= 1) {
        if (tid < s2) red[tid] = fmaxf(red[tid], red[tid + s2]);
        __syncthreads();
    }
    if (tid == 0) atomicMax(mxslot, __float_as_uint(red[0]));
}

// ---- scale (vectorized float4) --------------------------------------------
__global__ __launch_bounds__(256) void scale_k(float* __restrict__ D,
                                               const unsigned* __restrict__ mxslot)
{
    int idx = (blockIdx.x * 256 + threadIdx.x) * 4;
    float M = __uint_as_float(*mxslot);
    float4 d = *(float4*)(D + idx);
    d.x /= M; d.y /= M; d.z /= M; d.w /= M;
    *(float4*)(D + idx) = d;
}

// ---------------------------------------------------------------------------
extern "C" void kernel_launch(void* const* d_in, const int* in_sizes, int n_in,
                              void* d_out, int out_size, void* d_ws, size_t ws_size,
                              hipStream_t stream)
{
    (void)in_sizes; (void)n_in; (void)out_size; (void)ws_size;
    const float* x    = (const float*)d_in[0];
    const float* c1w  = (const float*)d_in[1];
    const float* c1b  = (const float*)d_in[2];
    const float* g1   = (const float*)d_in[3];
    const float* b1   = (const float*)d_in[4];
    const float* m1   = (const float*)d_in[5];
    const float* v1   = (const float*)d_in[6];
    const float* c2w  = (const float*)d_in[7];
    const float* c2b  = (const float*)d_in[8];
    const float* g2   = (const float*)d_in[9];
    const float* b2   = (const float*)d_in[10];
    const float* m2   = (const float*)d_in[11];
    const float* v2   = (const float*)d_in[12];
    const float* c3w  = (const float*)d_in[13];
    const float* c3b  = (const float*)d_in[14];
    const float* g3   = (const float*)d_in[15];
    const float* b3   = (const float*)d_in[16];
    const float* m3   = (const float*)d_in[17];
    const float* v3   = (const float*)d_in[18];
    const float* fw1  = (const float*)d_in[19];
    const float* fb1  = (const float*)d_in[20];
    const float* gf1  = (const float*)d_in[21];
    const float* bf1  = (const float*)d_in[22];
    const float* mf1  = (const float*)d_in[23];
    const float* vf1  = (const float*)d_in[24];
    const float* fw2  = (const float*)d_in[25];
    const float* fb2  = (const float*)d_in[26];
    const float* gf2  = (const float*)d_in[27];
    const float* bf2  = (const float*)d_in[28];
    const float* mf2  = (const float*)d_in[29];
    const float* vf2  = (const float*)d_in[30];
    const float* fw3  = (const float*)d_in[31];
    const float* fb3  = (const float*)d_in[32];
    const float* gf3  = (const float*)d_in[33];
    const float* bf3  = (const float*)d_in[34];
    const float* mf3  = (const float*)d_in[35];
    const float* vf3  = (const float*)d_in[36];

    float* ws = (float*)d_ws;
    // ---- ws layout (float offsets, 16B-aligned) ---------------------------
    float* E    = ws + 0;                                    // 65536
    float* sq   = ws + 65536;                                // 512
    float* f3v  = ws + 66048;                                // 65536
    unsigned* mx = (unsigned*)(ws + 131584);
    unsigned short* wT1b = (unsigned short*)(ws + 131600);   // 512 ush
    unsigned short* wT2b = (unsigned short*)(ws + 131856);   // 12288 ush
    unsigned short* wT3b = (unsigned short*)(ws + 138000);   // 49152 ush
    unsigned short* fw1b = (unsigned short*)(ws + 162576);   // 786432 ush
    unsigned short* fw2b = (unsigned short*)(ws + 555792);   // 131072 ush
    unsigned short* fw3b = (unsigned short*)(ws + 621328);   // 32768 ush
    unsigned short* out3b= (unsigned short*)(ws + 637712);   // 786432 ush
    unsigned short* a1b  = (unsigned short*)(ws + 1030928);  // 262144 ush
    unsigned short* a2b  = (unsigned short*)(ws + 1162000);  // 131072 ush

    float* out = (float*)d_out;

    repack_k<<<464, 256, 0, stream>>>(c1w, c2w, c3w, fw1, fw2, fw3,
                                      wT1b, wT2b, wT3b, fw1b, fw2b, fw3b, mx);
    conv_all<<<512, 512, 0, stream>>>(x, wT1b, wT2b, wT3b,
                                      c1b, g1, b1, m1, v1,
                                      c2b, g2, b2, m2, v2,
                                      c3b, g3, b3, m3, v3, out3b);
    fc_ks<<<dim3(32, 32), 256, 0, stream>>>(out3b, fw1b, fb1, gf1, bf1, mf1, vf1,
                                            a1b, nullptr, 1536, 512, 0);
    fc_ks<<<dim3(16, 32), 256, 0, stream>>>(a1b, fw2b, fb2, gf2, bf2, mf2, vf2,
                                            a2b, nullptr, 512, 256, 0);
    fc_ks<<<dim3(8, 32), 256, 0, stream>>>(a2b, fw3b, fb3, gf3, bf3, mf3, vf3,
                                           nullptr, f3v, 256, 128, 1);
    norm_k<<<512, 128, 0, stream>>>(f3v, E, sq);
    dist_k<<<dim3(32, 32), 256, 0, stream>>>(E, sq, out, mx);
    scale_k<<<256, 256, 0, stream>>>(out, mx);
}